// Round 8
// baseline (2016.984 us; speedup 1.0000x reference)
//
#include <hip/hip_runtime.h>
#include <hip/hip_bf16.h>

#define NPART 22
#define NDEG  21
#define NEDGE 462
#define HID   64
#define NLAYERS 4
#define NSTRIPB 29      // 16-edge strips per batch
#define MWS   68        // u32 row stride of wave-private m tile

typedef __attribute__((ext_vector_type(8))) short bf16x8;
typedef __attribute__((ext_vector_type(4))) float f32x4;
typedef __attribute__((ext_vector_type(4))) unsigned int u32x4;

__device__ __forceinline__ float silu_f(float v) {
    return __fdividef(v, 1.0f + __expf(-v));
}
__device__ __forceinline__ unsigned short bfu(float v) {
    return __bfloat16_as_ushort(__float2bfloat16(v));
}
__device__ __forceinline__ float bf2f(unsigned h) { return __uint_as_float(h << 16); }

__device__ __forceinline__ unsigned pack_hl(float v) {
    unsigned short h = bfu(v);
    float r = v - bf2f(h);
    return (unsigned)h | ((unsigned)bfu(r) << 16);
}
__device__ __forceinline__ void split8(const float* va, bf16x8& hi, bf16x8& lo) {
    #pragma unroll
    for (int i = 0; i < 8; ++i) {
        unsigned short h = bfu(va[i]);
        hi[i] = (short)h;
        lo[i] = (short)bfu(va[i] - bf2f(h));
    }
}

// ---- B-fragment prep: W2 / Wc1 per layer, MFMA layout, bf16 ----
__global__ void prep_wfrag(const float* __restrict__ edge_w2,
                           const float* __restrict__ coord_w1,
                           unsigned* __restrict__ wfrag)
{
    const int m = blockIdx.x;      // 0..7: L*2 + {0:W2, 1:Wc1}
    const int l = threadIdx.x;     // 0..63
    const int L = m >> 1;
    const float* W = (m & 1) ? (coord_w1 + L*HID*HID) : (edge_w2 + L*HID*HID);
    const int kg = l >> 4, j0 = l & 15;
    u32x4* ws4 = (u32x4*)wfrag;
    #pragma unroll
    for (int nt = 0; nt < 4; ++nt) {
        #pragma unroll
        for (int c = 0; c < 2; ++c) {
            u32x4 p;
            #pragma unroll
            for (int pi = 0; pi < 4; ++pi) {
                int k = c*32 + kg*8 + 2*pi;
                float v0 = W[k*HID + nt*16 + j0];
                float v1 = W[(k+1)*HID + nt*16 + j0];
                p[pi] = (unsigned)bfu(v0) | ((unsigned)bfu(v1) << 16);
            }
            ws4[m*512 + (nt*2 + c)*64 + l] = p;
        }
    }
}

// ---- init: h embedding, x copy, agg/dx zero, layer-0 Hr/Hc ----
__global__ __launch_bounds__(256, 4)
void k_init(const float* __restrict__ t_in, const float* __restrict__ xs,
            const float* __restrict__ h_init,
            const float* __restrict__ emb_w, const float* __restrict__ emb_b,
            const float* __restrict__ edge_w1, const float* __restrict__ edge_b1,
            float* __restrict__ xw, float* __restrict__ hw,
            float* __restrict__ Hrw, float* __restrict__ Hcw,
            float* __restrict__ aggw, float* __restrict__ dxw, int NT)
{
    __shared__ __align__(16) float hbuf[4][68];
    const int w = threadIdx.x >> 6, l = threadIdx.x & 63;
    const int n = blockIdx.x*4 + w;
    if (n >= NT) return;                       // no barriers in this kernel
    const int bidx = n / NPART, p = n - bidx*NPART;
    const int j = l;
    float hv = emb_b[j] + t_in[bidx]*emb_w[8*HID + j];
    #pragma unroll
    for (int k = 0; k < 8; ++k) hv += h_init[p*8 + k]*emb_w[k*HID + j];
    hw[n*HID + j] = hv;
    aggw[n*HID + j] = 0.f;
    hbuf[w][j] = hv;
    float accr = edge_b1[j], accc = 0.f;
    #pragma unroll 4
    for (int k = 0; k < HID; ++k) {
        float hk = hbuf[w][k];
        accr += hk*edge_w1[k*HID + j];
        accc += hk*edge_w1[(HID + k)*HID + j];
    }
    Hrw[n*HID + j] = accr;
    Hcw[n*HID + j] = accc;
    if (l < 3) { xw[n*3 + l] = xs[n*3 + l]; dxw[n*3 + l] = 0.f; }
}

// ---- edge kernel: one 16-edge strip per wave ----
__global__ __launch_bounds__(256, 4)
void k_edge(const float* __restrict__ edge_w1v,   // vrad base (= w1 + 128*HID)
            const float* __restrict__ edge_b2L,
            const float* __restrict__ coord_b1L,
            const float* __restrict__ coord_w2L,
            const unsigned* __restrict__ wfrag,
            const float* __restrict__ xs,
            const float* __restrict__ xw,
            const float* __restrict__ Hrw,
            const float* __restrict__ Hcw,
            float* __restrict__ aggw,
            float* __restrict__ dxw,
            int nstrips, int Lmat)
{
    __shared__ __align__(16) float    vecs[5][64];   // vrad,vea,vb2,vcb1,vcw2
    __shared__ __align__(16) unsigned mwall[4][16*MWS];
    __shared__ __align__(16) float    xst[4][2][68]; // x, x0 rows (wave's batch)
    __shared__ float scal_sw[4][16];

    const int tid = threadIdx.x, l = tid & 63, w = tid >> 6;
    const int kg = l >> 4, j0 = l & 15;

    for (int i = tid; i < 320; i += 256) {
        int a = i >> 6, o = i & 63; float v;
        if      (a == 0) v = edge_w1v[o];
        else if (a == 1) v = edge_w1v[64 + o];
        else if (a == 2) v = edge_b2L[o];
        else if (a == 3) v = coord_b1L[o];
        else             v = coord_w2L[o];
        vecs[a][o] = v;
    }
    __syncthreads();

    const int sid = blockIdx.x*4 + w;
    if (sid >= nstrips) return;
    const int batch = sid / NSTRIPB, s = sid - batch*NSTRIPB;
    const int e0 = s*16;
    const int ecnt = (NEDGE - e0 < 16) ? (NEDGE - e0) : 16;

    // stage this wave's batch coords (wave-private, same-wave ordering)
    {
        const int base = batch*(NPART*3);
        xst[w][0][l] = xw[base + l];
        xst[w][1][l] = xs[base + l];
        if (l < 2) { xst[w][0][64+l] = xw[base + 64 + l]; xst[w][1][64+l] = xs[base + 64 + l]; }
        if (l < 16) scal_sw[w][l] = 0.f;
    }

    int eg = e0 + j0; if (eg >= NEDGE) eg = NEDGE - 1;
    const int a  = eg / NDEG;
    const int r  = eg - a*NDEG;
    const int bb = r + (r >= a ? 1 : 0);
    float d0 = xst[w][0][a*3+0] - xst[w][0][bb*3+0];
    float d1 = xst[w][0][a*3+1] - xst[w][0][bb*3+1];
    float d2 = xst[w][0][a*3+2] - xst[w][0][bb*3+2];
    float rad = d0*d0 + d1*d1 + d2*d2;
    float inv = rsqrtf(rad + 1e-8f);
    float f0 = d0*inv, f1 = d1*inv, f2 = d2*inv;
    float g0 = xst[w][1][a*3+0] - xst[w][1][bb*3+0];
    float g1 = xst[w][1][a*3+1] - xst[w][1][bb*3+1];
    float g2 = xst[w][1][a*3+2] - xst[w][1][bb*3+2];
    float eav = g0*g0 + g1*g1 + g2*g2;

    // m1 A-fragments (registers)
    bf16x8 Ah[2], Al[2];
    {
        const float* hrp = Hrw + (size_t)(batch*NPART + a)*HID;
        const float* hcp = Hcw + (size_t)(batch*NPART + bb)*HID;
        #pragma unroll
        for (int c = 0; c < 2; ++c) {
            const int k0 = c*32 + kg*8;
            float4 ra = *(const float4*)(hrp + k0);
            float4 rb = *(const float4*)(hrp + k0 + 4);
            float4 ca = *(const float4*)(hcp + k0);
            float4 cb = *(const float4*)(hcp + k0 + 4);
            float4 va = *(const float4*)&vecs[0][k0];
            float4 vb = *(const float4*)&vecs[0][k0 + 4];
            float4 ua = *(const float4*)&vecs[1][k0];
            float4 ub = *(const float4*)&vecs[1][k0 + 4];
            float tv[8];
            tv[0] = silu_f(ra.x + ca.x + rad*va.x + eav*ua.x);
            tv[1] = silu_f(ra.y + ca.y + rad*va.y + eav*ua.y);
            tv[2] = silu_f(ra.z + ca.z + rad*va.z + eav*ua.z);
            tv[3] = silu_f(ra.w + ca.w + rad*va.w + eav*ua.w);
            tv[4] = silu_f(rb.x + cb.x + rad*vb.x + eav*ub.x);
            tv[5] = silu_f(rb.y + cb.y + rad*vb.y + eav*ub.y);
            tv[6] = silu_f(rb.z + cb.z + rad*vb.z + eav*ub.z);
            tv[7] = silu_f(rb.w + cb.w + rad*vb.w + eav*ub.w);
            split8(tv, Ah[c], Al[c]);
        }
    }

    const u32x4* ws4 = (const u32x4*)wfrag;
    #define BF(mat, nt, c) __builtin_bit_cast(bf16x8, ws4[(mat)*512 + ((nt)*2+(c))*64 + l])
    const int m0 = Lmat*2, m1m = Lmat*2 + 1;

    // GEMM1: m = m1 @ W2
    f32x4 acc[4];
    #pragma unroll
    for (int nt = 0; nt < 4; ++nt) {
        f32x4 z = {0.f, 0.f, 0.f, 0.f};
        bf16x8 b0 = BF(m0, nt, 0), b1 = BF(m0, nt, 1);
        z = __builtin_amdgcn_mfma_f32_16x16x32_bf16(Ah[0], b0, z, 0, 0, 0);
        z = __builtin_amdgcn_mfma_f32_16x16x32_bf16(Al[0], b0, z, 0, 0, 0);
        z = __builtin_amdgcn_mfma_f32_16x16x32_bf16(Ah[1], b1, z, 0, 0, 0);
        z = __builtin_amdgcn_mfma_f32_16x16x32_bf16(Al[1], b1, z, 0, 0, 0);
        acc[nt] = z;
    }

    // epilogue 1: silu+bias, pack to wave tile, agg global atomics
    int abn[4], emask[4];
    #pragma unroll
    for (int r2 = 0; r2 < 4; ++r2) {
        int e2 = kg*4 + r2;
        int eg2 = e0 + e2; if (eg2 >= NEDGE) eg2 = NEDGE - 1;
        abn[r2] = (batch*NPART + eg2/NDEG)*HID;
        emask[r2] = (e2 < ecnt);
    }
    unsigned* mw = mwall[w];
    #pragma unroll
    for (int nt = 0; nt < 4; ++nt) {
        int j = nt*16 + j0;
        float bv = vecs[2][j];
        #pragma unroll
        for (int r2 = 0; r2 < 4; ++r2) {
            float mv = silu_f(acc[nt][r2] + bv);
            mw[(kg*4 + r2)*MWS + j] = pack_hl(mv);
            if (emask[r2]) unsafeAtomicAdd(&aggw[abn[r2] + j], mv);
        }
    }

    // GEMM2 A-fragments from packed wave tile (transpose bounce)
    bf16x8 A2h[2], A2l[2];
    {
        const unsigned* arp = mw + j0*MWS;
        #pragma unroll
        for (int c = 0; c < 2; ++c) {
            const int k0 = c*32 + kg*8;
            u32x4 qa = *(const u32x4*)(arp + k0);
            u32x4 qb = *(const u32x4*)(arp + k0 + 4);
            u32x4 hw2, lw;
            hw2[0] = (qa[0] & 0xffffu) | (qa[1] << 16);
            hw2[1] = (qa[2] & 0xffffu) | (qa[3] << 16);
            hw2[2] = (qb[0] & 0xffffu) | (qb[1] << 16);
            hw2[3] = (qb[2] & 0xffffu) | (qb[3] << 16);
            lw[0] = (qa[0] >> 16) | (qa[1] & 0xffff0000u);
            lw[1] = (qa[2] >> 16) | (qa[3] & 0xffff0000u);
            lw[2] = (qb[0] >> 16) | (qb[1] & 0xffff0000u);
            lw[3] = (qb[2] >> 16) | (qb[3] & 0xffff0000u);
            A2h[c] = __builtin_bit_cast(bf16x8, hw2);
            A2l[c] = __builtin_bit_cast(bf16x8, lw);
        }
    }

    // GEMM2: c1 = m @ Wc1
    f32x4 acc2[4];
    #pragma unroll
    for (int nt = 0; nt < 4; ++nt) {
        f32x4 z = {0.f, 0.f, 0.f, 0.f};
        bf16x8 b0 = BF(m1m, nt, 0), b1 = BF(m1m, nt, 1);
        z = __builtin_amdgcn_mfma_f32_16x16x32_bf16(A2h[0], b0, z, 0, 0, 0);
        z = __builtin_amdgcn_mfma_f32_16x16x32_bf16(A2l[0], b0, z, 0, 0, 0);
        z = __builtin_amdgcn_mfma_f32_16x16x32_bf16(A2h[1], b1, z, 0, 0, 0);
        z = __builtin_amdgcn_mfma_f32_16x16x32_bf16(A2l[1], b1, z, 0, 0, 0);
        acc2[nt] = z;
    }
    #undef BF

    // epilogue 2: scal via 16-lane shuffle reduce, then dx global atomics
    float pr[4] = {0.f, 0.f, 0.f, 0.f};
    #pragma unroll
    for (int nt = 0; nt < 4; ++nt) {
        int j = nt*16 + j0;
        float cb = vecs[3][j], cw = vecs[4][j];
        #pragma unroll
        for (int r2 = 0; r2 < 4; ++r2)
            pr[r2] += silu_f(acc2[nt][r2] + cb) * cw;
    }
    #pragma unroll
    for (int off = 8; off > 0; off >>= 1) {
        #pragma unroll
        for (int r2 = 0; r2 < 4; ++r2)
            pr[r2] += __shfl_xor(pr[r2], off, 16);
    }
    if (j0 == 0) {
        #pragma unroll
        for (int r2 = 0; r2 < 4; ++r2)
            scal_sw[w][kg*4 + r2] = pr[r2];
    }
    if (l < ecnt) {
        float sc = scal_sw[w][l];
        float* dxp = dxw + (size_t)(batch*NPART + a)*3;
        unsafeAtomicAdd(dxp + 0, f0*sc);
        unsafeAtomicAdd(dxp + 1, f1*sc);
        unsafeAtomicAdd(dxp + 2, f2*sc);
    }
}

// ---- node kernel: node MLP + x update + next layer's Hr/Hc ----
__global__ __launch_bounds__(256, 4)
void k_node(const float* __restrict__ node_w1L, const float* __restrict__ node_b1L,
            const float* __restrict__ node_w2L, const float* __restrict__ node_b2L,
            const float* __restrict__ edge_w1n, const float* __restrict__ edge_b1n,
            float* __restrict__ xw, float* __restrict__ hw,
            float* __restrict__ Hrw, float* __restrict__ Hcw,
            float* __restrict__ aggw, float* __restrict__ dxw, int NT)
{
    __shared__ __align__(16) float hbuf[4][68], abuf[4][68];
    const int w = threadIdx.x >> 6, l = threadIdx.x & 63;
    const int n = blockIdx.x*4 + w;
    if (n >= NT) return;                      // no barriers in this kernel
    const int j = l;
    float hj = hw[n*HID + j];
    hbuf[w][j] = hj;
    abuf[w][j] = aggw[n*HID + j];
    float acc = node_b1L[j];
    #pragma unroll 4
    for (int k = 0; k < HID; ++k)
        acc += hbuf[w][k]*node_w1L[k*HID + j] + abuf[w][k]*node_w1L[(HID + k)*HID + j];
    float hn = silu_f(acc);
    abuf[w][j] = hn;
    float acc2 = node_b2L[j];
    #pragma unroll 4
    for (int k = 0; k < HID; ++k) acc2 += abuf[w][k]*node_w2L[k*HID + j];
    float hnew = hj + acc2;
    hw[n*HID + j] = hnew;
    aggw[n*HID + j] = 0.f;
    hbuf[w][j] = hnew;
    float accr = edge_b1n[j], accc = 0.f;
    #pragma unroll 4
    for (int k = 0; k < HID; ++k) {
        float hk = hbuf[w][k];
        accr += hk*edge_w1n[k*HID + j];
        accc += hk*edge_w1n[(HID + k)*HID + j];
    }
    Hrw[n*HID + j] = accr;
    Hcw[n*HID + j] = accc;
    if (l < 3) { xw[n*3 + l] += dxw[n*3 + l]; dxw[n*3 + l] = 0.f; }
}

// ---- final: vel = (x + dx - x0) - mean ----
__global__ void k_final(const float* __restrict__ xw, const float* __restrict__ dxw,
                        const float* __restrict__ xs, float* __restrict__ out)
{
    __shared__ float vbuf[66];
    __shared__ float mv[3];
    const int b = blockIdx.x, t = threadIdx.x;
    if (t < 66) vbuf[t] = xw[b*66 + t] + dxw[b*66 + t] - xs[b*66 + t];
    __syncthreads();
    if (t < 3) {
        float s = 0.f;
        #pragma unroll
        for (int p = 0; p < NPART; ++p) s += vbuf[p*3 + t];
        mv[t] = s / (float)NPART;
    }
    __syncthreads();
    if (t < 66) {
        int d = t % 3;                        // FIX: was mv[t] (OOB for t>=3)
        out[b*66 + t] = vbuf[t] - mv[d];
    }
}

extern "C" void kernel_launch(void* const* d_in, const int* in_sizes, int n_in,
                              void* d_out, int out_size, void* d_ws, size_t ws_size,
                              hipStream_t stream) {
    const float* t_in     = (const float*)d_in[0];
    const float* xs       = (const float*)d_in[1];
    const float* h_init   = (const float*)d_in[2];
    const float* emb_w    = (const float*)d_in[3];
    const float* emb_b    = (const float*)d_in[4];
    const float* edge_w1  = (const float*)d_in[7];
    const float* edge_b1  = (const float*)d_in[8];
    const float* edge_w2  = (const float*)d_in[9];
    const float* edge_b2  = (const float*)d_in[10];
    const float* node_w1  = (const float*)d_in[11];
    const float* node_b1  = (const float*)d_in[12];
    const float* node_w2  = (const float*)d_in[13];
    const float* node_b2  = (const float*)d_in[14];
    const float* coord_w1 = (const float*)d_in[15];
    const float* coord_b1 = (const float*)d_in[16];
    const float* coord_w2 = (const float*)d_in[17];
    float* outp = (float*)d_out;

    const int NB = in_sizes[0];
    const int NT = NB * NPART;
    float* xw   = (float*)d_ws;           // NT*3
    float* hw   = xw   + (size_t)NT*3;    // NT*64
    float* Hrw  = hw   + (size_t)NT*HID;
    float* Hcw  = Hrw  + (size_t)NT*HID;
    float* aggw = Hcw  + (size_t)NT*HID;
    float* dxw  = aggw + (size_t)NT*HID;  // NT*3
    unsigned* wfrag = (unsigned*)(dxw + (size_t)NT*3);

    const int nstrips = NB * NSTRIPB;
    const int gEdge = (nstrips + 3) / 4;
    const int gNode = (NT + 3) / 4;

    prep_wfrag<<<8, 64, 0, stream>>>(edge_w2, coord_w1, wfrag);
    k_init<<<gNode, 256, 0, stream>>>(t_in, xs, h_init, emb_w, emb_b,
                                      edge_w1, edge_b1,
                                      xw, hw, Hrw, Hcw, aggw, dxw, NT);
    for (int L = 0; L < NLAYERS; ++L) {
        k_edge<<<gEdge, 256, 0, stream>>>(
            edge_w1 + L*130*HID + 128*HID,
            edge_b2 + L*HID, coord_b1 + L*HID, coord_w2 + L*HID,
            wfrag, xs, xw, Hrw, Hcw, aggw, dxw, nstrips, L);
        if (L < NLAYERS - 1) {
            k_node<<<gNode, 256, 0, stream>>>(
                node_w1 + L*2*HID*HID, node_b1 + L*HID,
                node_w2 + L*HID*HID,   node_b2 + L*HID,
                edge_w1 + (L+1)*130*HID, edge_b1 + (L+1)*HID,
                xw, hw, Hrw, Hcw, aggw, dxw, NT);
        }
    }
    k_final<<<NB, 128, 0, stream>>>(xw, dxw, xs, outp);
}

// Round 9
// 1022.848 us; speedup vs baseline: 1.9719x; 1.9719x over previous
//
#include <hip/hip_runtime.h>
#include <hip/hip_bf16.h>

#define NPART 22
#define NDEG  21
#define NEDGE 462
#define HID   64
#define NLAYERS 4
#define NSTRIPB 29      // 16-edge strips per batch
#define MWS   68        // u32 row stride of wave-private m tile

typedef __attribute__((ext_vector_type(8))) short bf16x8;
typedef __attribute__((ext_vector_type(4))) float f32x4;
typedef __attribute__((ext_vector_type(4))) unsigned int u32x4;

__device__ __forceinline__ float silu_f(float v) {
    return __fdividef(v, 1.0f + __expf(-v));
}
__device__ __forceinline__ unsigned short bfu(float v) {
    return __bfloat16_as_ushort(__float2bfloat16(v));
}
__device__ __forceinline__ float bf2f(unsigned h) { return __uint_as_float(h << 16); }

__device__ __forceinline__ unsigned pack_hl(float v) {
    unsigned short h = bfu(v);
    float r = v - bf2f(h);
    return (unsigned)h | ((unsigned)bfu(r) << 16);
}
__device__ __forceinline__ void split8(const float* va, bf16x8& hi, bf16x8& lo) {
    #pragma unroll
    for (int i = 0; i < 8; ++i) {
        unsigned short h = bfu(va[i]);
        hi[i] = (short)h;
        lo[i] = (short)bfu(va[i] - bf2f(h));
    }
}

// ---- B-fragment prep: W2 / Wc1 per layer, MFMA layout, bf16 ----
__global__ void prep_wfrag(const float* __restrict__ edge_w2,
                           const float* __restrict__ coord_w1,
                           unsigned* __restrict__ wfrag)
{
    const int m = blockIdx.x;      // 0..7: L*2 + {0:W2, 1:Wc1}
    const int l = threadIdx.x;     // 0..63
    const int L = m >> 1;
    const float* W = (m & 1) ? (coord_w1 + L*HID*HID) : (edge_w2 + L*HID*HID);
    const int kg = l >> 4, j0 = l & 15;
    u32x4* ws4 = (u32x4*)wfrag;
    #pragma unroll
    for (int nt = 0; nt < 4; ++nt) {
        #pragma unroll
        for (int c = 0; c < 2; ++c) {
            u32x4 p;
            #pragma unroll
            for (int pi = 0; pi < 4; ++pi) {
                int k = c*32 + kg*8 + 2*pi;
                float v0 = W[k*HID + nt*16 + j0];
                float v1 = W[(k+1)*HID + nt*16 + j0];
                p[pi] = (unsigned)bfu(v0) | ((unsigned)bfu(v1) << 16);
            }
            ws4[m*512 + (nt*2 + c)*64 + l] = p;
        }
    }
}

// ---- init: h embedding, x copy, dx zero, layer-0 Hr/Hc ----
__global__ __launch_bounds__(256, 4)
void k_init(const float* __restrict__ t_in, const float* __restrict__ xs,
            const float* __restrict__ h_init,
            const float* __restrict__ emb_w, const float* __restrict__ emb_b,
            const float* __restrict__ edge_w1, const float* __restrict__ edge_b1,
            float* __restrict__ xw, float* __restrict__ hw,
            float* __restrict__ Hrw, float* __restrict__ Hcw,
            float* __restrict__ dxw, int NT)
{
    __shared__ __align__(16) float hbuf[4][68];
    const int w = threadIdx.x >> 6, l = threadIdx.x & 63;
    const int n = blockIdx.x*4 + w;
    if (n >= NT) return;                       // no barriers in this kernel
    const int bidx = n / NPART, p = n - bidx*NPART;
    const int j = l;
    float hv = emb_b[j] + t_in[bidx]*emb_w[8*HID + j];
    #pragma unroll
    for (int k = 0; k < 8; ++k) hv += h_init[p*8 + k]*emb_w[k*HID + j];
    hw[n*HID + j] = hv;
    hbuf[w][j] = hv;
    float accr = edge_b1[j], accc = 0.f;
    #pragma unroll 4
    for (int k = 0; k < HID; ++k) {
        float hk = hbuf[w][k];
        accr += hk*edge_w1[k*HID + j];
        accc += hk*edge_w1[(HID + k)*HID + j];
    }
    Hrw[n*HID + j] = accr;
    Hcw[n*HID + j] = accc;
    if (l < 3) { xw[n*3 + l] = xs[n*3 + l]; dxw[n*3 + l] = 0.f; }
}

// ---- edge kernel: one block per batch; 4 waves x ~7 strips; LDS reduction ----
__global__ __launch_bounds__(256, 4)
void k_edge(const float* __restrict__ edge_w1v,   // vrad base (= w1 + 128*HID)
            const float* __restrict__ edge_b2L,
            const float* __restrict__ coord_b1L,
            const float* __restrict__ coord_w2L,
            const unsigned* __restrict__ wfrag,
            const float* __restrict__ xs,
            const float* __restrict__ xw,
            const float* __restrict__ Hrw,
            const float* __restrict__ Hcw,
            float* __restrict__ aggw,
            float* __restrict__ dxw,
            int Lmat)
{
    __shared__ __align__(16) float    vecs[5][64];   // vrad,vea,vb2,vcb1,vcw2
    __shared__ __align__(16) unsigned mwall[4][16*MWS];
    __shared__ __align__(16) float    xst[2][68];    // x, x0 (this batch)
    __shared__ float scal_sw[4][16];
    __shared__ __align__(16) float    aggL[NPART][68];
    __shared__ float dxL[NPART*3 + 2];

    const int tid = threadIdx.x, l = tid & 63, w = tid >> 6;
    const int kg = l >> 4, j0 = l & 15;
    const int batch = blockIdx.x;

    for (int i = tid; i < 320; i += 256) {
        int a = i >> 6, o = i & 63; float v;
        if      (a == 0) v = edge_w1v[o];
        else if (a == 1) v = edge_w1v[64 + o];
        else if (a == 2) v = edge_b2L[o];
        else if (a == 3) v = coord_b1L[o];
        else             v = coord_w2L[o];
        vecs[a][o] = v;
    }
    for (int i = tid; i < NPART*68; i += 256) (&aggL[0][0])[i] = 0.f;
    if (tid < NPART*3) dxL[tid] = 0.f;
    if (tid < 66) {
        xst[0][tid] = xw[batch*66 + tid];
        xst[1][tid] = xs[batch*66 + tid];
    }
    __syncthreads();

    // hoist GEMM1 B-fragments (32 VGPR); GEMM2's loaded per strip
    const u32x4* ws4 = (const u32x4*)wfrag;
    #define BF(mat, nt, c) __builtin_bit_cast(bf16x8, ws4[(mat)*512 + ((nt)*2+(c))*64 + l])
    const int m0 = Lmat*2, m1m = Lmat*2 + 1;
    bf16x8 BW1[4][2];
    #pragma unroll
    for (int nt = 0; nt < 4; ++nt) {
        BW1[nt][0] = BF(m0, nt, 0);
        BW1[nt][1] = BF(m0, nt, 1);
    }

    for (int s = w; s < NSTRIPB; s += 4) {
        const int e0 = s*16;
        const int ecnt = (NEDGE - e0 < 16) ? (NEDGE - e0) : 16;

        int eg = e0 + j0; if (eg >= NEDGE) eg = NEDGE - 1;
        const int a  = eg / NDEG;
        const int r  = eg - a*NDEG;
        const int bb = r + (r >= a ? 1 : 0);
        float d0 = xst[0][a*3+0] - xst[0][bb*3+0];
        float d1 = xst[0][a*3+1] - xst[0][bb*3+1];
        float d2 = xst[0][a*3+2] - xst[0][bb*3+2];
        float rad = d0*d0 + d1*d1 + d2*d2;
        float inv = rsqrtf(rad + 1e-8f);
        float f0 = d0*inv, f1 = d1*inv, f2 = d2*inv;
        float g0 = xst[1][a*3+0] - xst[1][bb*3+0];
        float g1 = xst[1][a*3+1] - xst[1][bb*3+1];
        float g2 = xst[1][a*3+2] - xst[1][bb*3+2];
        float eav = g0*g0 + g1*g1 + g2*g2;

        // m1 A-fragments (registers)
        bf16x8 Ah[2], Al[2];
        {
            const float* hrp = Hrw + (size_t)(batch*NPART + a)*HID;
            const float* hcp = Hcw + (size_t)(batch*NPART + bb)*HID;
            #pragma unroll
            for (int c = 0; c < 2; ++c) {
                const int k0 = c*32 + kg*8;
                float4 ra = *(const float4*)(hrp + k0);
                float4 rb = *(const float4*)(hrp + k0 + 4);
                float4 ca = *(const float4*)(hcp + k0);
                float4 cb = *(const float4*)(hcp + k0 + 4);
                float4 va = *(const float4*)&vecs[0][k0];
                float4 vb = *(const float4*)&vecs[0][k0 + 4];
                float4 ua = *(const float4*)&vecs[1][k0];
                float4 ub = *(const float4*)&vecs[1][k0 + 4];
                float tv[8];
                tv[0] = silu_f(ra.x + ca.x + rad*va.x + eav*ua.x);
                tv[1] = silu_f(ra.y + ca.y + rad*va.y + eav*ua.y);
                tv[2] = silu_f(ra.z + ca.z + rad*va.z + eav*ua.z);
                tv[3] = silu_f(ra.w + ca.w + rad*va.w + eav*ua.w);
                tv[4] = silu_f(rb.x + cb.x + rad*vb.x + eav*ub.x);
                tv[5] = silu_f(rb.y + cb.y + rad*vb.y + eav*ub.y);
                tv[6] = silu_f(rb.z + cb.z + rad*vb.z + eav*ub.z);
                tv[7] = silu_f(rb.w + cb.w + rad*vb.w + eav*ub.w);
                split8(tv, Ah[c], Al[c]);
            }
        }

        // GEMM1: m = m1 @ W2
        f32x4 acc[4];
        #pragma unroll
        for (int nt = 0; nt < 4; ++nt) {
            f32x4 z = {0.f, 0.f, 0.f, 0.f};
            z = __builtin_amdgcn_mfma_f32_16x16x32_bf16(Ah[0], BW1[nt][0], z, 0, 0, 0);
            z = __builtin_amdgcn_mfma_f32_16x16x32_bf16(Al[0], BW1[nt][0], z, 0, 0, 0);
            z = __builtin_amdgcn_mfma_f32_16x16x32_bf16(Ah[1], BW1[nt][1], z, 0, 0, 0);
            z = __builtin_amdgcn_mfma_f32_16x16x32_bf16(Al[1], BW1[nt][1], z, 0, 0, 0);
            acc[nt] = z;
        }

        // issue GEMM2 B-fragment loads early (L2-hot); consumed after epilogue 1
        bf16x8 B2[4][2];
        #pragma unroll
        for (int nt = 0; nt < 4; ++nt) {
            B2[nt][0] = BF(m1m, nt, 0);
            B2[nt][1] = BF(m1m, nt, 1);
        }

        // epilogue 1: silu+bias, pack to wave tile, agg -> LDS atomics
        int abn[4], emask[4];
        #pragma unroll
        for (int r2 = 0; r2 < 4; ++r2) {
            int e2 = kg*4 + r2;
            int eg2 = e0 + e2; if (eg2 >= NEDGE) eg2 = NEDGE - 1;
            abn[r2] = eg2 / NDEG;
            emask[r2] = (e2 < ecnt);
        }
        unsigned* mw = mwall[w];
        #pragma unroll
        for (int nt = 0; nt < 4; ++nt) {
            int j = nt*16 + j0;
            float bv = vecs[2][j];
            #pragma unroll
            for (int r2 = 0; r2 < 4; ++r2) {
                float mv = silu_f(acc[nt][r2] + bv);
                mw[(kg*4 + r2)*MWS + j] = pack_hl(mv);
                if (emask[r2]) atomicAdd(&aggL[abn[r2]][j], mv);
            }
        }

        // GEMM2 A-fragments from packed wave tile (transpose bounce)
        bf16x8 A2h[2], A2l[2];
        {
            const unsigned* arp = mw + j0*MWS;
            #pragma unroll
            for (int c = 0; c < 2; ++c) {
                const int k0 = c*32 + kg*8;
                u32x4 qa = *(const u32x4*)(arp + k0);
                u32x4 qb = *(const u32x4*)(arp + k0 + 4);
                u32x4 hw2, lw;
                hw2[0] = (qa[0] & 0xffffu) | (qa[1] << 16);
                hw2[1] = (qa[2] & 0xffffu) | (qa[3] << 16);
                hw2[2] = (qb[0] & 0xffffu) | (qb[1] << 16);
                hw2[3] = (qb[2] & 0xffffu) | (qb[3] << 16);
                lw[0] = (qa[0] >> 16) | (qa[1] & 0xffff0000u);
                lw[1] = (qa[2] >> 16) | (qa[3] & 0xffff0000u);
                lw[2] = (qb[0] >> 16) | (qb[1] & 0xffff0000u);
                lw[3] = (qb[2] >> 16) | (qb[3] & 0xffff0000u);
                A2h[c] = __builtin_bit_cast(bf16x8, hw2);
                A2l[c] = __builtin_bit_cast(bf16x8, lw);
            }
        }

        // GEMM2: c1 = m @ Wc1
        f32x4 acc2[4];
        #pragma unroll
        for (int nt = 0; nt < 4; ++nt) {
            f32x4 z = {0.f, 0.f, 0.f, 0.f};
            z = __builtin_amdgcn_mfma_f32_16x16x32_bf16(A2h[0], B2[nt][0], z, 0, 0, 0);
            z = __builtin_amdgcn_mfma_f32_16x16x32_bf16(A2l[0], B2[nt][0], z, 0, 0, 0);
            z = __builtin_amdgcn_mfma_f32_16x16x32_bf16(A2h[1], B2[nt][1], z, 0, 0, 0);
            z = __builtin_amdgcn_mfma_f32_16x16x32_bf16(A2l[1], B2[nt][1], z, 0, 0, 0);
            acc2[nt] = z;
        }

        // epilogue 2: scal via 16-lane shuffle reduce, then dx -> LDS atomics
        float pr[4] = {0.f, 0.f, 0.f, 0.f};
        #pragma unroll
        for (int nt = 0; nt < 4; ++nt) {
            int j = nt*16 + j0;
            float cb = vecs[3][j], cw = vecs[4][j];
            #pragma unroll
            for (int r2 = 0; r2 < 4; ++r2)
                pr[r2] += silu_f(acc2[nt][r2] + cb) * cw;
        }
        #pragma unroll
        for (int off = 8; off > 0; off >>= 1) {
            #pragma unroll
            for (int r2 = 0; r2 < 4; ++r2)
                pr[r2] += __shfl_xor(pr[r2], off, 16);
        }
        if (j0 == 0) {
            #pragma unroll
            for (int r2 = 0; r2 < 4; ++r2)
                scal_sw[w][kg*4 + r2] = pr[r2];
        }
        if (l < ecnt) {
            float sc = scal_sw[w][l];
            atomicAdd(&dxL[a*3 + 0], f0*sc);
            atomicAdd(&dxL[a*3 + 1], f1*sc);
            atomicAdd(&dxL[a*3 + 2], f2*sc);
        }
    }
    #undef BF
    __syncthreads();

    // stream results out: plain coalesced stores, no global atomics
    for (int i = tid; i < NPART*HID; i += 256) {
        int p = i >> 6, j = i & 63;
        aggw[(size_t)(batch*NPART + p)*HID + j] = aggL[p][j];
    }
    if (tid < 66) dxw[batch*66 + tid] = dxL[tid];
}

// ---- node kernel: node MLP + x update + next layer's Hr/Hc ----
__global__ __launch_bounds__(256, 4)
void k_node(const float* __restrict__ node_w1L, const float* __restrict__ node_b1L,
            const float* __restrict__ node_w2L, const float* __restrict__ node_b2L,
            const float* __restrict__ edge_w1n, const float* __restrict__ edge_b1n,
            float* __restrict__ xw, float* __restrict__ hw,
            float* __restrict__ Hrw, float* __restrict__ Hcw,
            const float* __restrict__ aggw, const float* __restrict__ dxw, int NT)
{
    __shared__ __align__(16) float hbuf[4][68], abuf[4][68];
    const int w = threadIdx.x >> 6, l = threadIdx.x & 63;
    const int n = blockIdx.x*4 + w;
    if (n >= NT) return;                      // no barriers in this kernel
    const int j = l;
    float hj = hw[n*HID + j];
    hbuf[w][j] = hj;
    abuf[w][j] = aggw[n*HID + j];
    float acc = node_b1L[j];
    #pragma unroll 4
    for (int k = 0; k < HID; ++k)
        acc += hbuf[w][k]*node_w1L[k*HID + j] + abuf[w][k]*node_w1L[(HID + k)*HID + j];
    float hn = silu_f(acc);
    abuf[w][j] = hn;
    float acc2 = node_b2L[j];
    #pragma unroll 4
    for (int k = 0; k < HID; ++k) acc2 += abuf[w][k]*node_w2L[k*HID + j];
    float hnew = hj + acc2;
    hw[n*HID + j] = hnew;
    hbuf[w][j] = hnew;
    float accr = edge_b1n[j], accc = 0.f;
    #pragma unroll 4
    for (int k = 0; k < HID; ++k) {
        float hk = hbuf[w][k];
        accr += hk*edge_w1n[k*HID + j];
        accc += hk*edge_w1n[(HID + k)*HID + j];
    }
    Hrw[n*HID + j] = accr;
    Hcw[n*HID + j] = accc;
    if (l < 3) xw[n*3 + l] += dxw[n*3 + l];
}

// ---- final: vel = (x + dx - x0) - mean ----
__global__ void k_final(const float* __restrict__ xw, const float* __restrict__ dxw,
                        const float* __restrict__ xs, float* __restrict__ out)
{
    __shared__ float vbuf[66];
    __shared__ float mv[3];
    const int b = blockIdx.x, t = threadIdx.x;
    if (t < 66) vbuf[t] = xw[b*66 + t] + dxw[b*66 + t] - xs[b*66 + t];
    __syncthreads();
    if (t < 3) {
        float s = 0.f;
        #pragma unroll
        for (int p = 0; p < NPART; ++p) s += vbuf[p*3 + t];
        mv[t] = s / (float)NPART;
    }
    __syncthreads();
    if (t < 66) out[b*66 + t] = vbuf[t] - mv[t % 3];
}

extern "C" void kernel_launch(void* const* d_in, const int* in_sizes, int n_in,
                              void* d_out, int out_size, void* d_ws, size_t ws_size,
                              hipStream_t stream) {
    const float* t_in     = (const float*)d_in[0];
    const float* xs       = (const float*)d_in[1];
    const float* h_init   = (const float*)d_in[2];
    const float* emb_w    = (const float*)d_in[3];
    const float* emb_b    = (const float*)d_in[4];
    const float* edge_w1  = (const float*)d_in[7];
    const float* edge_b1  = (const float*)d_in[8];
    const float* edge_w2  = (const float*)d_in[9];
    const float* edge_b2  = (const float*)d_in[10];
    const float* node_w1  = (const float*)d_in[11];
    const float* node_b1  = (const float*)d_in[12];
    const float* node_w2  = (const float*)d_in[13];
    const float* node_b2  = (const float*)d_in[14];
    const float* coord_w1 = (const float*)d_in[15];
    const float* coord_b1 = (const float*)d_in[16];
    const float* coord_w2 = (const float*)d_in[17];
    float* outp = (float*)d_out;

    const int NB = in_sizes[0];
    const int NT = NB * NPART;
    float* xw   = (float*)d_ws;           // NT*3
    float* hw   = xw   + (size_t)NT*3;    // NT*64
    float* Hrw  = hw   + (size_t)NT*HID;
    float* Hcw  = Hrw  + (size_t)NT*HID;
    float* aggw = Hcw  + (size_t)NT*HID;
    float* dxw  = aggw + (size_t)NT*HID;  // NT*3
    unsigned* wfrag = (unsigned*)(dxw + (size_t)NT*3);

    const int gNode = (NT + 3) / 4;

    prep_wfrag<<<8, 64, 0, stream>>>(edge_w2, coord_w1, wfrag);
    k_init<<<gNode, 256, 0, stream>>>(t_in, xs, h_init, emb_w, emb_b,
                                      edge_w1, edge_b1,
                                      xw, hw, Hrw, Hcw, dxw, NT);
    for (int L = 0; L < NLAYERS; ++L) {
        k_edge<<<NB, 256, 0, stream>>>(
            edge_w1 + L*130*HID + 128*HID,
            edge_b2 + L*HID, coord_b1 + L*HID, coord_w2 + L*HID,
            wfrag, xs, xw, Hrw, Hcw, aggw, dxw, L);
        if (L < NLAYERS - 1) {
            k_node<<<gNode, 256, 0, stream>>>(
                node_w1 + L*2*HID*HID, node_b1 + L*HID,
                node_w2 + L*HID*HID,   node_b2 + L*HID,
                edge_w1 + (L+1)*130*HID, edge_b1 + (L+1)*HID,
                xw, hw, Hrw, Hcw, aggw, dxw, NT);
        }
    }
    k_final<<<NB, 128, 0, stream>>>(xw, dxw, xs, outp);
}

// Round 10
// 999.813 us; speedup vs baseline: 2.0174x; 1.0230x over previous
//
#include <hip/hip_runtime.h>
#include <hip/hip_bf16.h>

#define NPART 22
#define NDEG  21
#define NEDGE 462
#define HID   64
#define NLAYERS 4
#define NSTRIPB 29      // 16-edge strips per batch
#define MWS   68        // u32 row stride of wave-private m tile

typedef __attribute__((ext_vector_type(8))) short bf16x8;
typedef __attribute__((ext_vector_type(4))) float f32x4;
typedef __attribute__((ext_vector_type(4))) unsigned int u32x4;

__device__ __forceinline__ float silu_f(float v) {
    return __fdividef(v, 1.0f + __expf(-v));
}
__device__ __forceinline__ unsigned short bfu(float v) {
    return __bfloat16_as_ushort(__float2bfloat16(v));
}
__device__ __forceinline__ float bf2f(unsigned h) { return __uint_as_float(h << 16); }

__device__ __forceinline__ unsigned pack_hl(float v) {
    unsigned short h = bfu(v);
    float r = v - bf2f(h);
    return (unsigned)h | ((unsigned)bfu(r) << 16);
}
__device__ __forceinline__ void split8(const float* va, bf16x8& hi, bf16x8& lo) {
    #pragma unroll
    for (int i = 0; i < 8; ++i) {
        unsigned short h = bfu(va[i]);
        hi[i] = (short)h;
        lo[i] = (short)bfu(va[i] - bf2f(h));
    }
}

// ---- B-fragment prep: W2 / Wc1 per layer, MFMA layout, bf16 ----
__global__ void prep_wfrag(const float* __restrict__ edge_w2,
                           const float* __restrict__ coord_w1,
                           unsigned* __restrict__ wfrag)
{
    const int m = blockIdx.x;      // 0..7: L*2 + {0:W2, 1:Wc1}
    const int l = threadIdx.x;     // 0..63
    const int L = m >> 1;
    const float* W = (m & 1) ? (coord_w1 + L*HID*HID) : (edge_w2 + L*HID*HID);
    const int kg = l >> 4, j0 = l & 15;
    u32x4* ws4 = (u32x4*)wfrag;
    #pragma unroll
    for (int nt = 0; nt < 4; ++nt) {
        #pragma unroll
        for (int c = 0; c < 2; ++c) {
            u32x4 p;
            #pragma unroll
            for (int pi = 0; pi < 4; ++pi) {
                int k = c*32 + kg*8 + 2*pi;
                float v0 = W[k*HID + nt*16 + j0];
                float v1 = W[(k+1)*HID + nt*16 + j0];
                p[pi] = (unsigned)bfu(v0) | ((unsigned)bfu(v1) << 16);
            }
            ws4[m*512 + (nt*2 + c)*64 + l] = p;
        }
    }
}

// ---- init: h embedding, x copy, dx zero, layer-0 Hr/Hc ----
__global__ __launch_bounds__(256, 4)
void k_init(const float* __restrict__ t_in, const float* __restrict__ xs,
            const float* __restrict__ h_init,
            const float* __restrict__ emb_w, const float* __restrict__ emb_b,
            const float* __restrict__ edge_w1, const float* __restrict__ edge_b1,
            float* __restrict__ xw, float* __restrict__ hw,
            float* __restrict__ Hrw, float* __restrict__ Hcw,
            float* __restrict__ dxw, int NT)
{
    __shared__ __align__(16) float hbuf[4][68];
    const int w = threadIdx.x >> 6, l = threadIdx.x & 63;
    const int n = blockIdx.x*4 + w;
    if (n >= NT) return;                       // no barriers in this kernel
    const int bidx = n / NPART, p = n - bidx*NPART;
    const int j = l;
    float hv = emb_b[j] + t_in[bidx]*emb_w[8*HID + j];
    #pragma unroll
    for (int k = 0; k < 8; ++k) hv += h_init[p*8 + k]*emb_w[k*HID + j];
    hw[n*HID + j] = hv;
    hbuf[w][j] = hv;
    float accr = edge_b1[j], accc = 0.f;
    #pragma unroll 4
    for (int k = 0; k < HID; ++k) {
        float hk = hbuf[w][k];
        accr += hk*edge_w1[k*HID + j];
        accc += hk*edge_w1[(HID + k)*HID + j];
    }
    Hrw[n*HID + j] = accr;
    Hcw[n*HID + j] = accc;
    if (l < 3) { xw[n*3 + l] = xs[n*3 + l]; dxw[n*3 + l] = 0.f; }
}

// ---- edge kernel: one block per batch; 4 waves x ~7 strips; LDS reduction ----
__global__ __launch_bounds__(256, 3)
void k_edge(const float* __restrict__ edge_w1v,   // vrad base (= w1 + 128*HID)
            const float* __restrict__ edge_b2L,
            const float* __restrict__ coord_b1L,
            const float* __restrict__ coord_w2L,
            const unsigned* __restrict__ wfrag,
            const float* __restrict__ xs,
            const float* __restrict__ xw,
            const float* __restrict__ Hrw,
            const float* __restrict__ Hcw,
            float* __restrict__ aggw,
            float* __restrict__ dxw,
            int Lmat)
{
    __shared__ __align__(16) float    vecs[5][64];   // vrad,vea,vb2,vcb1,vcw2
    __shared__ __align__(16) unsigned mwall[4][16*MWS];
    __shared__ __align__(16) float    xst[2][68];    // x, x0 (this batch)
    __shared__ float scal_sw[4][16];
    __shared__ __align__(16) float    aggL[NPART][68];
    __shared__ float dxL[NPART*3 + 2];

    const int tid = threadIdx.x, l = tid & 63, w = tid >> 6;
    const int kg = l >> 4, j0 = l & 15;
    const int batch = blockIdx.x;

    for (int i = tid; i < 320; i += 256) {
        int a = i >> 6, o = i & 63; float v;
        if      (a == 0) v = edge_w1v[o];
        else if (a == 1) v = edge_w1v[64 + o];
        else if (a == 2) v = edge_b2L[o];
        else if (a == 3) v = coord_b1L[o];
        else             v = coord_w2L[o];
        vecs[a][o] = v;
    }
    for (int i = tid; i < NPART*68; i += 256) (&aggL[0][0])[i] = 0.f;
    if (tid < NPART*3) dxL[tid] = 0.f;
    if (tid < 66) {
        xst[0][tid] = xw[batch*66 + tid];
        xst[1][tid] = xs[batch*66 + tid];
    }
    __syncthreads();

    // hoist BOTH B-fragment sets (64 VGPR) — fits under the 3-waves/SIMD cap
    const u32x4* ws4 = (const u32x4*)wfrag;
    #define BF(mat, nt, c) __builtin_bit_cast(bf16x8, ws4[(mat)*512 + ((nt)*2+(c))*64 + l])
    const int m0 = Lmat*2, m1m = Lmat*2 + 1;
    bf16x8 BW1[4][2], B2[4][2];
    #pragma unroll
    for (int nt = 0; nt < 4; ++nt) {
        BW1[nt][0] = BF(m0, nt, 0);
        BW1[nt][1] = BF(m0, nt, 1);
        B2[nt][0]  = BF(m1m, nt, 0);
        B2[nt][1]  = BF(m1m, nt, 1);
    }
    #undef BF

    for (int s = w; s < NSTRIPB; s += 4) {
        const int e0 = s*16;
        const int ecnt = (NEDGE - e0 < 16) ? (NEDGE - e0) : 16;

        int eg = e0 + j0; if (eg >= NEDGE) eg = NEDGE - 1;
        const int a  = eg / NDEG;
        const int r  = eg - a*NDEG;
        const int bb = r + (r >= a ? 1 : 0);
        float d0 = xst[0][a*3+0] - xst[0][bb*3+0];
        float d1 = xst[0][a*3+1] - xst[0][bb*3+1];
        float d2 = xst[0][a*3+2] - xst[0][bb*3+2];
        float rad = d0*d0 + d1*d1 + d2*d2;
        float inv = rsqrtf(rad + 1e-8f);
        float f0 = d0*inv, f1 = d1*inv, f2 = d2*inv;
        float g0 = xst[1][a*3+0] - xst[1][bb*3+0];
        float g1 = xst[1][a*3+1] - xst[1][bb*3+1];
        float g2 = xst[1][a*3+2] - xst[1][bb*3+2];
        float eav = g0*g0 + g1*g1 + g2*g2;

        // m1 A-fragments (registers)
        bf16x8 Ah[2], Al[2];
        {
            const float* hrp = Hrw + (size_t)(batch*NPART + a)*HID;
            const float* hcp = Hcw + (size_t)(batch*NPART + bb)*HID;
            #pragma unroll
            for (int c = 0; c < 2; ++c) {
                const int k0 = c*32 + kg*8;
                float4 ra = *(const float4*)(hrp + k0);
                float4 rb = *(const float4*)(hrp + k0 + 4);
                float4 ca = *(const float4*)(hcp + k0);
                float4 cb = *(const float4*)(hcp + k0 + 4);
                float4 va = *(const float4*)&vecs[0][k0];
                float4 vb = *(const float4*)&vecs[0][k0 + 4];
                float4 ua = *(const float4*)&vecs[1][k0];
                float4 ub = *(const float4*)&vecs[1][k0 + 4];
                float tv[8];
                tv[0] = silu_f(ra.x + ca.x + rad*va.x + eav*ua.x);
                tv[1] = silu_f(ra.y + ca.y + rad*va.y + eav*ua.y);
                tv[2] = silu_f(ra.z + ca.z + rad*va.z + eav*ua.z);
                tv[3] = silu_f(ra.w + ca.w + rad*va.w + eav*ua.w);
                tv[4] = silu_f(rb.x + cb.x + rad*vb.x + eav*ub.x);
                tv[5] = silu_f(rb.y + cb.y + rad*vb.y + eav*ub.y);
                tv[6] = silu_f(rb.z + cb.z + rad*vb.z + eav*ub.z);
                tv[7] = silu_f(rb.w + cb.w + rad*vb.w + eav*ub.w);
                split8(tv, Ah[c], Al[c]);
            }
        }

        // GEMM1: m = m1 @ W2
        f32x4 acc[4];
        #pragma unroll
        for (int nt = 0; nt < 4; ++nt) {
            f32x4 z = {0.f, 0.f, 0.f, 0.f};
            z = __builtin_amdgcn_mfma_f32_16x16x32_bf16(Ah[0], BW1[nt][0], z, 0, 0, 0);
            z = __builtin_amdgcn_mfma_f32_16x16x32_bf16(Al[0], BW1[nt][0], z, 0, 0, 0);
            z = __builtin_amdgcn_mfma_f32_16x16x32_bf16(Ah[1], BW1[nt][1], z, 0, 0, 0);
            z = __builtin_amdgcn_mfma_f32_16x16x32_bf16(Al[1], BW1[nt][1], z, 0, 0, 0);
            acc[nt] = z;
        }

        // epilogue 1: silu+bias, pack to wave tile, agg -> LDS atomics
        int abn[4], emask[4];
        #pragma unroll
        for (int r2 = 0; r2 < 4; ++r2) {
            int e2 = kg*4 + r2;
            int eg2 = e0 + e2; if (eg2 >= NEDGE) eg2 = NEDGE - 1;
            abn[r2] = eg2 / NDEG;
            emask[r2] = (e2 < ecnt);
        }
        unsigned* mw = mwall[w];
        #pragma unroll
        for (int nt = 0; nt < 4; ++nt) {
            int j = nt*16 + j0;
            float bv = vecs[2][j];
            #pragma unroll
            for (int r2 = 0; r2 < 4; ++r2) {
                float mv = silu_f(acc[nt][r2] + bv);
                mw[(kg*4 + r2)*MWS + j] = pack_hl(mv);
                if (emask[r2]) atomicAdd(&aggL[abn[r2]][j], mv);
            }
        }

        // GEMM2 A-fragments from packed wave tile (transpose bounce)
        bf16x8 A2h[2], A2l[2];
        {
            const unsigned* arp = mw + j0*MWS;
            #pragma unroll
            for (int c = 0; c < 2; ++c) {
                const int k0 = c*32 + kg*8;
                u32x4 qa = *(const u32x4*)(arp + k0);
                u32x4 qb = *(const u32x4*)(arp + k0 + 4);
                u32x4 hw2, lw;
                hw2[0] = (qa[0] & 0xffffu) | (qa[1] << 16);
                hw2[1] = (qa[2] & 0xffffu) | (qa[3] << 16);
                hw2[2] = (qb[0] & 0xffffu) | (qb[1] << 16);
                hw2[3] = (qb[2] & 0xffffu) | (qb[3] << 16);
                lw[0] = (qa[0] >> 16) | (qa[1] & 0xffff0000u);
                lw[1] = (qa[2] >> 16) | (qa[3] & 0xffff0000u);
                lw[2] = (qb[0] >> 16) | (qb[1] & 0xffff0000u);
                lw[3] = (qb[2] >> 16) | (qb[3] & 0xffff0000u);
                A2h[c] = __builtin_bit_cast(bf16x8, hw2);
                A2l[c] = __builtin_bit_cast(bf16x8, lw);
            }
        }

        // GEMM2: c1 = m @ Wc1
        f32x4 acc2[4];
        #pragma unroll
        for (int nt = 0; nt < 4; ++nt) {
            f32x4 z = {0.f, 0.f, 0.f, 0.f};
            z = __builtin_amdgcn_mfma_f32_16x16x32_bf16(A2h[0], B2[nt][0], z, 0, 0, 0);
            z = __builtin_amdgcn_mfma_f32_16x16x32_bf16(A2l[0], B2[nt][0], z, 0, 0, 0);
            z = __builtin_amdgcn_mfma_f32_16x16x32_bf16(A2h[1], B2[nt][1], z, 0, 0, 0);
            z = __builtin_amdgcn_mfma_f32_16x16x32_bf16(A2l[1], B2[nt][1], z, 0, 0, 0);
            acc2[nt] = z;
        }

        // epilogue 2: scal via 16-lane shuffle reduce, then dx -> LDS atomics
        float pr[4] = {0.f, 0.f, 0.f, 0.f};
        #pragma unroll
        for (int nt = 0; nt < 4; ++nt) {
            int j = nt*16 + j0;
            float cb = vecs[3][j], cw = vecs[4][j];
            #pragma unroll
            for (int r2 = 0; r2 < 4; ++r2)
                pr[r2] += silu_f(acc2[nt][r2] + cb) * cw;
        }
        #pragma unroll
        for (int off = 8; off > 0; off >>= 1) {
            #pragma unroll
            for (int r2 = 0; r2 < 4; ++r2)
                pr[r2] += __shfl_xor(pr[r2], off, 16);
        }
        if (j0 == 0) {
            #pragma unroll
            for (int r2 = 0; r2 < 4; ++r2)
                scal_sw[w][kg*4 + r2] = pr[r2];
        }
        if (l < ecnt) {
            float sc = scal_sw[w][l];
            atomicAdd(&dxL[a*3 + 0], f0*sc);
            atomicAdd(&dxL[a*3 + 1], f1*sc);
            atomicAdd(&dxL[a*3 + 2], f2*sc);
        }
    }
    __syncthreads();

    // stream results out: plain coalesced stores, no global atomics
    for (int i = tid; i < NPART*HID; i += 256) {
        int p = i >> 6, j = i & 63;
        aggw[(size_t)(batch*NPART + p)*HID + j] = aggL[p][j];
    }
    if (tid < 66) dxw[batch*66 + tid] = dxL[tid];
}

// ---- node kernel: node MLP + x update + next layer's Hr/Hc ----
__global__ __launch_bounds__(256, 4)
void k_node(const float* __restrict__ node_w1L, const float* __restrict__ node_b1L,
            const float* __restrict__ node_w2L, const float* __restrict__ node_b2L,
            const float* __restrict__ edge_w1n, const float* __restrict__ edge_b1n,
            float* __restrict__ xw, float* __restrict__ hw,
            float* __restrict__ Hrw, float* __restrict__ Hcw,
            const float* __restrict__ aggw, const float* __restrict__ dxw, int NT)
{
    __shared__ __align__(16) float hbuf[4][68], abuf[4][68];
    const int w = threadIdx.x >> 6, l = threadIdx.x & 63;
    const int n = blockIdx.x*4 + w;
    if (n >= NT) return;                      // no barriers in this kernel
    const int j = l;
    float hj = hw[n*HID + j];
    hbuf[w][j] = hj;
    abuf[w][j] = aggw[n*HID + j];
    float acc = node_b1L[j];
    #pragma unroll 4
    for (int k = 0; k < HID; ++k)
        acc += hbuf[w][k]*node_w1L[k*HID + j] + abuf[w][k]*node_w1L[(HID + k)*HID + j];
    float hn = silu_f(acc);
    abuf[w][j] = hn;
    float acc2 = node_b2L[j];
    #pragma unroll 4
    for (int k = 0; k < HID; ++k) acc2 += abuf[w][k]*node_w2L[k*HID + j];
    float hnew = hj + acc2;
    hw[n*HID + j] = hnew;
    hbuf[w][j] = hnew;
    float accr = edge_b1n[j], accc = 0.f;
    #pragma unroll 4
    for (int k = 0; k < HID; ++k) {
        float hk = hbuf[w][k];
        accr += hk*edge_w1n[k*HID + j];
        accc += hk*edge_w1n[(HID + k)*HID + j];
    }
    Hrw[n*HID + j] = accr;
    Hcw[n*HID + j] = accc;
    if (l < 3) xw[n*3 + l] += dxw[n*3 + l];
}

// ---- final: vel = (x + dx - x0) - mean ----
__global__ void k_final(const float* __restrict__ xw, const float* __restrict__ dxw,
                        const float* __restrict__ xs, float* __restrict__ out)
{
    __shared__ float vbuf[66];
    __shared__ float mv[3];
    const int b = blockIdx.x, t = threadIdx.x;
    if (t < 66) vbuf[t] = xw[b*66 + t] + dxw[b*66 + t] - xs[b*66 + t];
    __syncthreads();
    if (t < 3) {
        float s = 0.f;
        #pragma unroll
        for (int p = 0; p < NPART; ++p) s += vbuf[p*3 + t];
        mv[t] = s / (float)NPART;
    }
    __syncthreads();
    if (t < 66) out[b*66 + t] = vbuf[t] - mv[t % 3];
}

extern "C" void kernel_launch(void* const* d_in, const int* in_sizes, int n_in,
                              void* d_out, int out_size, void* d_ws, size_t ws_size,
                              hipStream_t stream) {
    const float* t_in     = (const float*)d_in[0];
    const float* xs       = (const float*)d_in[1];
    const float* h_init   = (const float*)d_in[2];
    const float* emb_w    = (const float*)d_in[3];
    const float* emb_b    = (const float*)d_in[4];
    const float* edge_w1  = (const float*)d_in[7];
    const float* edge_b1  = (const float*)d_in[8];
    const float* edge_w2  = (const float*)d_in[9];
    const float* edge_b2  = (const float*)d_in[10];
    const float* node_w1  = (const float*)d_in[11];
    const float* node_b1  = (const float*)d_in[12];
    const float* node_w2  = (const float*)d_in[13];
    const float* node_b2  = (const float*)d_in[14];
    const float* coord_w1 = (const float*)d_in[15];
    const float* coord_b1 = (const float*)d_in[16];
    const float* coord_w2 = (const float*)d_in[17];
    float* outp = (float*)d_out;

    const int NB = in_sizes[0];
    const int NT = NB * NPART;
    float* xw   = (float*)d_ws;           // NT*3
    float* hw   = xw   + (size_t)NT*3;    // NT*64
    float* Hrw  = hw   + (size_t)NT*HID;
    float* Hcw  = Hrw  + (size_t)NT*HID;
    float* aggw = Hcw  + (size_t)NT*HID;
    float* dxw  = aggw + (size_t)NT*HID;  // NT*3
    unsigned* wfrag = (unsigned*)(dxw + (size_t)NT*3);

    const int gNode = (NT + 3) / 4;

    prep_wfrag<<<8, 64, 0, stream>>>(edge_w2, coord_w1, wfrag);
    k_init<<<gNode, 256, 0, stream>>>(t_in, xs, h_init, emb_w, emb_b,
                                      edge_w1, edge_b1,
                                      xw, hw, Hrw, Hcw, dxw, NT);
    for (int L = 0; L < NLAYERS; ++L) {
        k_edge<<<NB, 256, 0, stream>>>(
            edge_w1 + L*130*HID + 128*HID,
            edge_b2 + L*HID, coord_b1 + L*HID, coord_w2 + L*HID,
            wfrag, xs, xw, Hrw, Hcw, aggw, dxw, L);
        if (L < NLAYERS - 1) {
            k_node<<<gNode, 256, 0, stream>>>(
                node_w1 + L*2*HID*HID, node_b1 + L*HID,
                node_w2 + L*HID*HID,   node_b2 + L*HID,
                edge_w1 + (L+1)*130*HID, edge_b1 + (L+1)*HID,
                xw, hw, Hrw, Hcw, aggw, dxw, NT);
        }
    }
    k_final<<<NB, 128, 0, stream>>>(xw, dxw, xs, outp);
}

// Round 11
// 959.166 us; speedup vs baseline: 2.1029x; 1.0424x over previous
//
#include <hip/hip_runtime.h>
#include <hip/hip_bf16.h>

#define NPART 22
#define NDEG  21
#define NEDGE 462
#define HID   64
#define NLAYERS 4
#define NSTRIPB 29      // 16-edge strips per batch
#define MWS   68        // u32 row stride of wave-private m tile

typedef __attribute__((ext_vector_type(8))) short bf16x8;
typedef __attribute__((ext_vector_type(4))) float f32x4;
typedef __attribute__((ext_vector_type(4))) unsigned int u32x4;

__device__ __forceinline__ float silu_f(float v) {
    return __fdividef(v, 1.0f + __expf(-v));
}
__device__ __forceinline__ unsigned short bfu(float v) {
    return __bfloat16_as_ushort(__float2bfloat16(v));
}
__device__ __forceinline__ float bf2f(unsigned h) { return __uint_as_float(h << 16); }

__device__ __forceinline__ unsigned pack_hl(float v) {
    unsigned short h = bfu(v);
    float r = v - bf2f(h);
    return (unsigned)h | ((unsigned)bfu(r) << 16);
}
__device__ __forceinline__ void split8(const float* va, bf16x8& hi, bf16x8& lo) {
    #pragma unroll
    for (int i = 0; i < 8; ++i) {
        unsigned short h = bfu(va[i]);
        hi[i] = (short)h;
        lo[i] = (short)bfu(va[i] - bf2f(h));
    }
}

// ---- B-fragment prep: W2 / Wc1 per layer, MFMA layout, bf16 ----
__global__ void prep_wfrag(const float* __restrict__ edge_w2,
                           const float* __restrict__ coord_w1,
                           unsigned* __restrict__ wfrag)
{
    const int m = blockIdx.x;      // 0..7: L*2 + {0:W2, 1:Wc1}
    const int l = threadIdx.x;     // 0..63
    const int L = m >> 1;
    const float* W = (m & 1) ? (coord_w1 + L*HID*HID) : (edge_w2 + L*HID*HID);
    const int kg = l >> 4, j0 = l & 15;
    u32x4* ws4 = (u32x4*)wfrag;
    #pragma unroll
    for (int nt = 0; nt < 4; ++nt) {
        #pragma unroll
        for (int c = 0; c < 2; ++c) {
            u32x4 p;
            #pragma unroll
            for (int pi = 0; pi < 4; ++pi) {
                int k = c*32 + kg*8 + 2*pi;
                float v0 = W[k*HID + nt*16 + j0];
                float v1 = W[(k+1)*HID + nt*16 + j0];
                p[pi] = (unsigned)bfu(v0) | ((unsigned)bfu(v1) << 16);
            }
            ws4[m*512 + (nt*2 + c)*64 + l] = p;
        }
    }
}

// ---- init: h embedding, x copy, dx zero, layer-0 Hr/Hc ----
__global__ __launch_bounds__(256, 4)
void k_init(const float* __restrict__ t_in, const float* __restrict__ xs,
            const float* __restrict__ h_init,
            const float* __restrict__ emb_w, const float* __restrict__ emb_b,
            const float* __restrict__ edge_w1, const float* __restrict__ edge_b1,
            float* __restrict__ xw, float* __restrict__ hw,
            float* __restrict__ Hrw, float* __restrict__ Hcw,
            float* __restrict__ dxw, int NT)
{
    __shared__ __align__(16) float hbuf[4][68];
    const int w = threadIdx.x >> 6, l = threadIdx.x & 63;
    const int n = blockIdx.x*4 + w;
    if (n >= NT) return;                       // no barriers in this kernel
    const int bidx = n / NPART, p = n - bidx*NPART;
    const int j = l;
    float hv = emb_b[j] + t_in[bidx]*emb_w[8*HID + j];
    #pragma unroll
    for (int k = 0; k < 8; ++k) hv += h_init[p*8 + k]*emb_w[k*HID + j];
    hw[n*HID + j] = hv;
    hbuf[w][j] = hv;
    float accr = edge_b1[j], accc = 0.f;
    #pragma unroll 4
    for (int k = 0; k < HID; ++k) {
        float hk = hbuf[w][k];
        accr += hk*edge_w1[k*HID + j];
        accc += hk*edge_w1[(HID + k)*HID + j];
    }
    Hrw[n*HID + j] = accr;
    Hcw[n*HID + j] = accc;
    if (l < 3) { xw[n*3 + l] = xs[n*3 + l]; dxw[n*3 + l] = 0.f; }
}

// ---- edge kernel: one block per batch; 4 waves x ~7 strips; LDS reduction ----
__global__ __launch_bounds__(256, 4)
void k_edge(const float* __restrict__ edge_w1v,   // vrad base (= w1 + 128*HID)
            const float* __restrict__ edge_b2L,
            const float* __restrict__ coord_b1L,
            const float* __restrict__ coord_w2L,
            const unsigned* __restrict__ wfrag,
            const float* __restrict__ xs,
            const float* __restrict__ xw,
            const float* __restrict__ Hrw,
            const float* __restrict__ Hcw,
            float* __restrict__ aggw,
            float* __restrict__ dxw,
            int Lmat)
{
    __shared__ __align__(16) float    vecs[5][64];   // vrad,vea,vb2,vcb1,vcw2
    __shared__ __align__(16) unsigned mwall[4][16*MWS];
    __shared__ __align__(16) float    xst[2][68];    // x, x0 (this batch)
    __shared__ float scal_sw[4][16];
    __shared__ __align__(16) float    aggL[NPART][68];
    __shared__ float dxL[NPART*3 + 2];

    const int tid = threadIdx.x, l = tid & 63, w = tid >> 6;
    const int kg = l >> 4, j0 = l & 15;
    const int batch = blockIdx.x;

    for (int i = tid; i < 320; i += 256) {
        int a = i >> 6, o = i & 63; float v;
        if      (a == 0) v = edge_w1v[o];
        else if (a == 1) v = edge_w1v[64 + o];
        else if (a == 2) v = edge_b2L[o];
        else if (a == 3) v = coord_b1L[o];
        else             v = coord_w2L[o];
        vecs[a][o] = v;
    }
    for (int i = tid; i < NPART*68; i += 256) (&aggL[0][0])[i] = 0.f;
    if (tid < NPART*3) dxL[tid] = 0.f;
    if (tid < 66) {
        xst[0][tid] = xw[batch*66 + tid];
        xst[1][tid] = xs[batch*66 + tid];
    }
    __syncthreads();

    // per-lane fragment base pointers into wfrag (L2-hot). Loaded PER STRIP
    // (asm-opaqued to defeat LICM) so only ~32 frag VGPRs are live at a time.
    const u32x4* ws4 = (const u32x4*)wfrag;
    const u32x4* wb1_0 = ws4 + (size_t)(Lmat*2    )*512 + l;
    const u32x4* wb2_0 = ws4 + (size_t)(Lmat*2 + 1)*512 + l;

    for (int s = w; s < NSTRIPB; s += 4) {
        const int e0 = s*16;
        const int ecnt = (NEDGE - e0 < 16) ? (NEDGE - e0) : 16;

        // opaque copies: compiler cannot prove loop-invariance -> no re-hoist
        const u32x4* wb1 = wb1_0;
        const u32x4* wb2 = wb2_0;
        asm volatile("" : "+v"(wb1));
        asm volatile("" : "+v"(wb2));

        // issue GEMM1 B-fragment loads now; latency hides under geometry+silu
        bf16x8 BW1[4][2];
        #pragma unroll
        for (int nt = 0; nt < 4; ++nt) {
            BW1[nt][0] = __builtin_bit_cast(bf16x8, wb1[(nt*2 + 0)*64]);
            BW1[nt][1] = __builtin_bit_cast(bf16x8, wb1[(nt*2 + 1)*64]);
        }

        int eg = e0 + j0; if (eg >= NEDGE) eg = NEDGE - 1;
        const int a  = eg / NDEG;
        const int r  = eg - a*NDEG;
        const int bb = r + (r >= a ? 1 : 0);
        float d0 = xst[0][a*3+0] - xst[0][bb*3+0];
        float d1 = xst[0][a*3+1] - xst[0][bb*3+1];
        float d2 = xst[0][a*3+2] - xst[0][bb*3+2];
        float rad = d0*d0 + d1*d1 + d2*d2;
        float inv = rsqrtf(rad + 1e-8f);
        float f0 = d0*inv, f1 = d1*inv, f2 = d2*inv;
        float g0 = xst[1][a*3+0] - xst[1][bb*3+0];
        float g1 = xst[1][a*3+1] - xst[1][bb*3+1];
        float g2 = xst[1][a*3+2] - xst[1][bb*3+2];
        float eav = g0*g0 + g1*g1 + g2*g2;

        // m1 A-fragments (registers)
        bf16x8 Ah[2], Al[2];
        {
            const float* hrp = Hrw + (size_t)(batch*NPART + a)*HID;
            const float* hcp = Hcw + (size_t)(batch*NPART + bb)*HID;
            #pragma unroll
            for (int c = 0; c < 2; ++c) {
                const int k0 = c*32 + kg*8;
                float4 ra = *(const float4*)(hrp + k0);
                float4 rb = *(const float4*)(hrp + k0 + 4);
                float4 ca = *(const float4*)(hcp + k0);
                float4 cb = *(const float4*)(hcp + k0 + 4);
                float4 va = *(const float4*)&vecs[0][k0];
                float4 vb = *(const float4*)&vecs[0][k0 + 4];
                float4 ua = *(const float4*)&vecs[1][k0];
                float4 ub = *(const float4*)&vecs[1][k0 + 4];
                float tv[8];
                tv[0] = silu_f(ra.x + ca.x + rad*va.x + eav*ua.x);
                tv[1] = silu_f(ra.y + ca.y + rad*va.y + eav*ua.y);
                tv[2] = silu_f(ra.z + ca.z + rad*va.z + eav*ua.z);
                tv[3] = silu_f(ra.w + ca.w + rad*va.w + eav*ua.w);
                tv[4] = silu_f(rb.x + cb.x + rad*vb.x + eav*ub.x);
                tv[5] = silu_f(rb.y + cb.y + rad*vb.y + eav*ub.y);
                tv[6] = silu_f(rb.z + cb.z + rad*vb.z + eav*ub.z);
                tv[7] = silu_f(rb.w + cb.w + rad*vb.w + eav*ub.w);
                split8(tv, Ah[c], Al[c]);
            }
        }

        // GEMM1: m = m1 @ W2
        f32x4 acc[4];
        #pragma unroll
        for (int nt = 0; nt < 4; ++nt) {
            f32x4 z = {0.f, 0.f, 0.f, 0.f};
            z = __builtin_amdgcn_mfma_f32_16x16x32_bf16(Ah[0], BW1[nt][0], z, 0, 0, 0);
            z = __builtin_amdgcn_mfma_f32_16x16x32_bf16(Al[0], BW1[nt][0], z, 0, 0, 0);
            z = __builtin_amdgcn_mfma_f32_16x16x32_bf16(Ah[1], BW1[nt][1], z, 0, 0, 0);
            z = __builtin_amdgcn_mfma_f32_16x16x32_bf16(Al[1], BW1[nt][1], z, 0, 0, 0);
            acc[nt] = z;
        }

        // issue GEMM2 B-fragment loads; latency hides under epilogue 1
        bf16x8 B2[4][2];
        #pragma unroll
        for (int nt = 0; nt < 4; ++nt) {
            B2[nt][0] = __builtin_bit_cast(bf16x8, wb2[(nt*2 + 0)*64]);
            B2[nt][1] = __builtin_bit_cast(bf16x8, wb2[(nt*2 + 1)*64]);
        }

        // epilogue 1: silu+bias, pack to wave tile, agg -> LDS atomics
        int abn[4], emask[4];
        #pragma unroll
        for (int r2 = 0; r2 < 4; ++r2) {
            int e2 = kg*4 + r2;
            int eg2 = e0 + e2; if (eg2 >= NEDGE) eg2 = NEDGE - 1;
            abn[r2] = eg2 / NDEG;
            emask[r2] = (e2 < ecnt);
        }
        unsigned* mw = mwall[w];
        #pragma unroll
        for (int nt = 0; nt < 4; ++nt) {
            int j = nt*16 + j0;
            float bv = vecs[2][j];
            #pragma unroll
            for (int r2 = 0; r2 < 4; ++r2) {
                float mv = silu_f(acc[nt][r2] + bv);
                mw[(kg*4 + r2)*MWS + j] = pack_hl(mv);
                if (emask[r2]) atomicAdd(&aggL[abn[r2]][j], mv);
            }
        }

        // GEMM2 A-fragments from packed wave tile (transpose bounce)
        bf16x8 A2h[2], A2l[2];
        {
            const unsigned* arp = mw + j0*MWS;
            #pragma unroll
            for (int c = 0; c < 2; ++c) {
                const int k0 = c*32 + kg*8;
                u32x4 qa = *(const u32x4*)(arp + k0);
                u32x4 qb = *(const u32x4*)(arp + k0 + 4);
                u32x4 hw2, lw;
                hw2[0] = (qa[0] & 0xffffu) | (qa[1] << 16);
                hw2[1] = (qa[2] & 0xffffu) | (qa[3] << 16);
                hw2[2] = (qb[0] & 0xffffu) | (qb[1] << 16);
                hw2[3] = (qb[2] & 0xffffu) | (qb[3] << 16);
                lw[0] = (qa[0] >> 16) | (qa[1] & 0xffff0000u);
                lw[1] = (qa[2] >> 16) | (qa[3] & 0xffff0000u);
                lw[2] = (qb[0] >> 16) | (qb[1] & 0xffff0000u);
                lw[3] = (qb[2] >> 16) | (qb[3] & 0xffff0000u);
                A2h[c] = __builtin_bit_cast(bf16x8, hw2);
                A2l[c] = __builtin_bit_cast(bf16x8, lw);
            }
        }

        // GEMM2: c1 = m @ Wc1
        f32x4 acc2[4];
        #pragma unroll
        for (int nt = 0; nt < 4; ++nt) {
            f32x4 z = {0.f, 0.f, 0.f, 0.f};
            z = __builtin_amdgcn_mfma_f32_16x16x32_bf16(A2h[0], B2[nt][0], z, 0, 0, 0);
            z = __builtin_amdgcn_mfma_f32_16x16x32_bf16(A2l[0], B2[nt][0], z, 0, 0, 0);
            z = __builtin_amdgcn_mfma_f32_16x16x32_bf16(A2h[1], B2[nt][1], z, 0, 0, 0);
            z = __builtin_amdgcn_mfma_f32_16x16x32_bf16(A2l[1], B2[nt][1], z, 0, 0, 0);
            acc2[nt] = z;
        }

        // epilogue 2: scal via 16-lane shuffle reduce, then dx -> LDS atomics
        float pr[4] = {0.f, 0.f, 0.f, 0.f};
        #pragma unroll
        for (int nt = 0; nt < 4; ++nt) {
            int j = nt*16 + j0;
            float cb = vecs[3][j], cw = vecs[4][j];
            #pragma unroll
            for (int r2 = 0; r2 < 4; ++r2)
                pr[r2] += silu_f(acc2[nt][r2] + cb) * cw;
        }
        #pragma unroll
        for (int off = 8; off > 0; off >>= 1) {
            #pragma unroll
            for (int r2 = 0; r2 < 4; ++r2)
                pr[r2] += __shfl_xor(pr[r2], off, 16);
        }
        if (j0 == 0) {
            #pragma unroll
            for (int r2 = 0; r2 < 4; ++r2)
                scal_sw[w][kg*4 + r2] = pr[r2];
        }
        if (l < ecnt) {
            float sc = scal_sw[w][l];
            atomicAdd(&dxL[a*3 + 0], f0*sc);
            atomicAdd(&dxL[a*3 + 1], f1*sc);
            atomicAdd(&dxL[a*3 + 2], f2*sc);
        }
    }
    __syncthreads();

    // stream results out: plain coalesced stores, no global atomics
    for (int i = tid; i < NPART*HID; i += 256) {
        int p = i >> 6, j = i & 63;
        aggw[(size_t)(batch*NPART + p)*HID + j] = aggL[p][j];
    }
    if (tid < 66) dxw[batch*66 + tid] = dxL[tid];
}

// ---- node kernel: node MLP + x update + next layer's Hr/Hc ----
__global__ __launch_bounds__(256, 4)
void k_node(const float* __restrict__ node_w1L, const float* __restrict__ node_b1L,
            const float* __restrict__ node_w2L, const float* __restrict__ node_b2L,
            const float* __restrict__ edge_w1n, const float* __restrict__ edge_b1n,
            float* __restrict__ xw, float* __restrict__ hw,
            float* __restrict__ Hrw, float* __restrict__ Hcw,
            const float* __restrict__ aggw, const float* __restrict__ dxw, int NT)
{
    __shared__ __align__(16) float hbuf[4][68], abuf[4][68];
    const int w = threadIdx.x >> 6, l = threadIdx.x & 63;
    const int n = blockIdx.x*4 + w;
    if (n >= NT) return;                      // no barriers in this kernel
    const int j = l;
    float hj = hw[n*HID + j];
    hbuf[w][j] = hj;
    abuf[w][j] = aggw[n*HID + j];
    float acc = node_b1L[j];
    #pragma unroll 4
    for (int k = 0; k < HID; ++k)
        acc += hbuf[w][k]*node_w1L[k*HID + j] + abuf[w][k]*node_w1L[(HID + k)*HID + j];
    float hn = silu_f(acc);
    abuf[w][j] = hn;
    float acc2 = node_b2L[j];
    #pragma unroll 4
    for (int k = 0; k < HID; ++k) acc2 += abuf[w][k]*node_w2L[k*HID + j];
    float hnew = hj + acc2;
    hw[n*HID + j] = hnew;
    hbuf[w][j] = hnew;
    float accr = edge_b1n[j], accc = 0.f;
    #pragma unroll 4
    for (int k = 0; k < HID; ++k) {
        float hk = hbuf[w][k];
        accr += hk*edge_w1n[k*HID + j];
        accc += hk*edge_w1n[(HID + k)*HID + j];
    }
    Hrw[n*HID + j] = accr;
    Hcw[n*HID + j] = accc;
    if (l < 3) xw[n*3 + l] += dxw[n*3 + l];
}

// ---- final: vel = (x + dx - x0) - mean ----
__global__ void k_final(const float* __restrict__ xw, const float* __restrict__ dxw,
                        const float* __restrict__ xs, float* __restrict__ out)
{
    __shared__ float vbuf[66];
    __shared__ float mv[3];
    const int b = blockIdx.x, t = threadIdx.x;
    if (t < 66) vbuf[t] = xw[b*66 + t] + dxw[b*66 + t] - xs[b*66 + t];
    __syncthreads();
    if (t < 3) {
        float s = 0.f;
        #pragma unroll
        for (int p = 0; p < NPART; ++p) s += vbuf[p*3 + t];
        mv[t] = s / (float)NPART;
    }
    __syncthreads();
    if (t < 66) out[b*66 + t] = vbuf[t] - mv[t % 3];
}

extern "C" void kernel_launch(void* const* d_in, const int* in_sizes, int n_in,
                              void* d_out, int out_size, void* d_ws, size_t ws_size,
                              hipStream_t stream) {
    const float* t_in     = (const float*)d_in[0];
    const float* xs       = (const float*)d_in[1];
    const float* h_init   = (const float*)d_in[2];
    const float* emb_w    = (const float*)d_in[3];
    const float* emb_b    = (const float*)d_in[4];
    const float* edge_w1  = (const float*)d_in[7];
    const float* edge_b1  = (const float*)d_in[8];
    const float* edge_w2  = (const float*)d_in[9];
    const float* edge_b2  = (const float*)d_in[10];
    const float* node_w1  = (const float*)d_in[11];
    const float* node_b1  = (const float*)d_in[12];
    const float* node_w2  = (const float*)d_in[13];
    const float* node_b2  = (const float*)d_in[14];
    const float* coord_w1 = (const float*)d_in[15];
    const float* coord_b1 = (const float*)d_in[16];
    const float* coord_w2 = (const float*)d_in[17];
    float* outp = (float*)d_out;

    const int NB = in_sizes[0];
    const int NT = NB * NPART;
    float* xw   = (float*)d_ws;           // NT*3
    float* hw   = xw   + (size_t)NT*3;    // NT*64
    float* Hrw  = hw   + (size_t)NT*HID;
    float* Hcw  = Hrw  + (size_t)NT*HID;
    float* aggw = Hcw  + (size_t)NT*HID;
    float* dxw  = aggw + (size_t)NT*HID;  // NT*3
    unsigned* wfrag = (unsigned*)(dxw + (size_t)NT*3);

    const int gNode = (NT + 3) / 4;

    prep_wfrag<<<8, 64, 0, stream>>>(edge_w2, coord_w1, wfrag);
    k_init<<<gNode, 256, 0, stream>>>(t_in, xs, h_init, emb_w, emb_b,
                                      edge_w1, edge_b1,
                                      xw, hw, Hrw, Hcw, dxw, NT);
    for (int L = 0; L < NLAYERS; ++L) {
        k_edge<<<NB, 256, 0, stream>>>(
            edge_w1 + L*130*HID + 128*HID,
            edge_b2 + L*HID, coord_b1 + L*HID, coord_w2 + L*HID,
            wfrag, xs, xw, Hrw, Hcw, aggw, dxw, L);
        if (L < NLAYERS - 1) {
            k_node<<<gNode, 256, 0, stream>>>(
                node_w1 + L*2*HID*HID, node_b1 + L*HID,
                node_w2 + L*HID*HID,   node_b2 + L*HID,
                edge_w1 + (L+1)*130*HID, edge_b1 + (L+1)*HID,
                xw, hw, Hrw, Hcw, aggw, dxw, NT);
        }
    }
    k_final<<<NB, 128, 0, stream>>>(xw, dxw, xs, outp);
}

// Round 12
// 952.174 us; speedup vs baseline: 2.1183x; 1.0073x over previous
//
#include <hip/hip_runtime.h>
#include <hip/hip_bf16.h>

#define NPART 22
#define NDEG  21
#define NEDGE 462
#define HID   64
#define NLAYERS 4
#define NSTRIPB 29      // 16-edge strips per batch
#define MW2S  72        // u16 row stride of wave-private m tile (144 B, 16B-mult)

typedef __attribute__((ext_vector_type(8))) short bf16x8;
typedef __attribute__((ext_vector_type(4))) float f32x4;
typedef __attribute__((ext_vector_type(4))) unsigned int u32x4;

__device__ __forceinline__ float silu_f(float v) {
    return __fdividef(v, 1.0f + __expf(-v));
}
__device__ __forceinline__ unsigned short bfu(float v) {
    return __bfloat16_as_ushort(__float2bfloat16(v));
}
__device__ __forceinline__ float bf2f(unsigned h) { return __uint_as_float(h << 16); }

__device__ __forceinline__ void split8(const float* va, bf16x8& hi, bf16x8& lo) {
    #pragma unroll
    for (int i = 0; i < 8; ++i) {
        unsigned short h = bfu(va[i]);
        hi[i] = (short)h;
        lo[i] = (short)bfu(va[i] - bf2f(h));
    }
}

// ---- B-fragment prep: W2 / Wc1 per layer, MFMA layout, bf16 ----
__global__ void prep_wfrag(const float* __restrict__ edge_w2,
                           const float* __restrict__ coord_w1,
                           unsigned* __restrict__ wfrag)
{
    const int m = blockIdx.x;      // 0..7: L*2 + {0:W2, 1:Wc1}
    const int l = threadIdx.x;     // 0..63
    const int L = m >> 1;
    const float* W = (m & 1) ? (coord_w1 + L*HID*HID) : (edge_w2 + L*HID*HID);
    const int kg = l >> 4, j0 = l & 15;
    u32x4* ws4 = (u32x4*)wfrag;
    #pragma unroll
    for (int nt = 0; nt < 4; ++nt) {
        #pragma unroll
        for (int c = 0; c < 2; ++c) {
            u32x4 p;
            #pragma unroll
            for (int pi = 0; pi < 4; ++pi) {
                int k = c*32 + kg*8 + 2*pi;
                float v0 = W[k*HID + nt*16 + j0];
                float v1 = W[(k+1)*HID + nt*16 + j0];
                p[pi] = (unsigned)bfu(v0) | ((unsigned)bfu(v1) << 16);
            }
            ws4[m*512 + (nt*2 + c)*64 + l] = p;
        }
    }
}

// ---- init: h embedding, x copy, dx zero, layer-0 Hr/Hc ----
__global__ __launch_bounds__(256, 4)
void k_init(const float* __restrict__ t_in, const float* __restrict__ xs,
            const float* __restrict__ h_init,
            const float* __restrict__ emb_w, const float* __restrict__ emb_b,
            const float* __restrict__ edge_w1, const float* __restrict__ edge_b1,
            float* __restrict__ xw, float* __restrict__ hw,
            float* __restrict__ Hrw, float* __restrict__ Hcw,
            float* __restrict__ dxw, int NT)
{
    __shared__ __align__(16) float hbuf[4][68];
    const int w = threadIdx.x >> 6, l = threadIdx.x & 63;
    const int n = blockIdx.x*4 + w;
    if (n >= NT) return;                       // no barriers in this kernel
    const int bidx = n / NPART, p = n - bidx*NPART;
    const int j = l;
    float hv = emb_b[j] + t_in[bidx]*emb_w[8*HID + j];
    #pragma unroll
    for (int k = 0; k < 8; ++k) hv += h_init[p*8 + k]*emb_w[k*HID + j];
    hw[n*HID + j] = hv;
    hbuf[w][j] = hv;
    float accr = edge_b1[j], accc = 0.f;
    #pragma unroll 4
    for (int k = 0; k < HID; ++k) {
        float hk = hbuf[w][k];
        accr += hk*edge_w1[k*HID + j];
        accc += hk*edge_w1[(HID + k)*HID + j];
    }
    Hrw[n*HID + j] = accr;
    Hcw[n*HID + j] = accc;
    if (l < 3) { xw[n*3 + l] = xs[n*3 + l]; dxw[n*3 + l] = 0.f; }
}

// ---- edge kernel: one block per batch; 4 waves x ~7 strips; LDS reduction ----
__global__ __launch_bounds__(256, 4)
void k_edge(const float* __restrict__ edge_w1v,   // vrad base (= w1 + 128*HID)
            const float* __restrict__ edge_b2L,
            const float* __restrict__ coord_b1L,
            const float* __restrict__ coord_w2L,
            const unsigned* __restrict__ wfrag,
            const float* __restrict__ xs,
            const float* __restrict__ xw,
            const float* __restrict__ Hrw,
            const float* __restrict__ Hcw,
            float* __restrict__ aggw,
            float* __restrict__ dxw,
            int Lmat)
{
    __shared__ __align__(16) float vecs[5][64];          // vrad,vea,vb2,vcb1,vcw2
    __shared__ __align__(16) unsigned short mwall[4][16*MW2S]; // bf16 m tiles
    __shared__ __align__(16) float xst[2][68];           // x, x0 (this batch)
    __shared__ float scal_sw[4][16];
    __shared__ __align__(16) float aggL[NPART][68];
    __shared__ float dxL[NPART*3 + 2];

    const int tid = threadIdx.x, l = tid & 63, w = tid >> 6;
    const int kg = l >> 4, j0 = l & 15;
    const int batch = blockIdx.x;

    for (int i = tid; i < 320; i += 256) {
        int a = i >> 6, o = i & 63; float v;
        if      (a == 0) v = edge_w1v[o];
        else if (a == 1) v = edge_w1v[64 + o];
        else if (a == 2) v = edge_b2L[o];
        else if (a == 3) v = coord_b1L[o];
        else             v = coord_w2L[o];
        vecs[a][o] = v;
    }
    for (int i = tid; i < NPART*68; i += 256) (&aggL[0][0])[i] = 0.f;
    if (tid < NPART*3) dxL[tid] = 0.f;
    if (tid < 66) {
        xst[0][tid] = xw[batch*66 + tid];
        xst[1][tid] = xs[batch*66 + tid];
    }
    __syncthreads();

    // per-lane fragment base pointers into wfrag (L2-hot), loaded PER STRIP
    // (asm-opaqued to defeat LICM) so frag VGPRs are short-lived.
    const u32x4* ws4 = (const u32x4*)wfrag;
    const u32x4* wb1_0 = ws4 + (size_t)(Lmat*2    )*512 + l;
    const u32x4* wb2_0 = ws4 + (size_t)(Lmat*2 + 1)*512 + l;

    for (int s = w; s < NSTRIPB; s += 4) {
        const int e0 = s*16;
        const int ecnt = (NEDGE - e0 < 16) ? (NEDGE - e0) : 16;

        const u32x4* wb1 = wb1_0;
        const u32x4* wb2 = wb2_0;
        asm volatile("" : "+v"(wb1));
        asm volatile("" : "+v"(wb2));

        // issue GEMM1 B-fragment loads now; latency hides under geometry+silu
        bf16x8 BW1[4][2];
        #pragma unroll
        for (int nt = 0; nt < 4; ++nt) {
            BW1[nt][0] = __builtin_bit_cast(bf16x8, wb1[(nt*2 + 0)*64]);
            BW1[nt][1] = __builtin_bit_cast(bf16x8, wb1[(nt*2 + 1)*64]);
        }

        int eg = e0 + j0; if (eg >= NEDGE) eg = NEDGE - 1;
        const int a  = eg / NDEG;
        const int r  = eg - a*NDEG;
        const int bb = r + (r >= a ? 1 : 0);
        float d0 = xst[0][a*3+0] - xst[0][bb*3+0];
        float d1 = xst[0][a*3+1] - xst[0][bb*3+1];
        float d2 = xst[0][a*3+2] - xst[0][bb*3+2];
        float rad = d0*d0 + d1*d1 + d2*d2;
        float inv = rsqrtf(rad + 1e-8f);
        float f0 = d0*inv, f1 = d1*inv, f2 = d2*inv;
        float g0 = xst[1][a*3+0] - xst[1][bb*3+0];
        float g1 = xst[1][a*3+1] - xst[1][bb*3+1];
        float g2 = xst[1][a*3+2] - xst[1][bb*3+2];
        float eav = g0*g0 + g1*g1 + g2*g2;

        // m1 A-fragments (registers), split hi/lo for accuracy of h-chain
        bf16x8 Ah[2], Al[2];
        {
            const float* hrp = Hrw + (size_t)(batch*NPART + a)*HID;
            const float* hcp = Hcw + (size_t)(batch*NPART + bb)*HID;
            #pragma unroll
            for (int c = 0; c < 2; ++c) {
                const int k0 = c*32 + kg*8;
                float4 ra = *(const float4*)(hrp + k0);
                float4 rb = *(const float4*)(hrp + k0 + 4);
                float4 ca = *(const float4*)(hcp + k0);
                float4 cb = *(const float4*)(hcp + k0 + 4);
                float4 va = *(const float4*)&vecs[0][k0];
                float4 vb = *(const float4*)&vecs[0][k0 + 4];
                float4 ua = *(const float4*)&vecs[1][k0];
                float4 ub = *(const float4*)&vecs[1][k0 + 4];
                float tv[8];
                tv[0] = silu_f(ra.x + ca.x + rad*va.x + eav*ua.x);
                tv[1] = silu_f(ra.y + ca.y + rad*va.y + eav*ua.y);
                tv[2] = silu_f(ra.z + ca.z + rad*va.z + eav*ua.z);
                tv[3] = silu_f(ra.w + ca.w + rad*va.w + eav*ua.w);
                tv[4] = silu_f(rb.x + cb.x + rad*vb.x + eav*ub.x);
                tv[5] = silu_f(rb.y + cb.y + rad*vb.y + eav*ub.y);
                tv[6] = silu_f(rb.z + cb.z + rad*vb.z + eav*ub.z);
                tv[7] = silu_f(rb.w + cb.w + rad*vb.w + eav*ub.w);
                split8(tv, Ah[c], Al[c]);
            }
        }

        // GEMM1: m = m1 @ W2  (split A x hi W)
        f32x4 acc[4];
        #pragma unroll
        for (int nt = 0; nt < 4; ++nt) {
            f32x4 z = {0.f, 0.f, 0.f, 0.f};
            z = __builtin_amdgcn_mfma_f32_16x16x32_bf16(Ah[0], BW1[nt][0], z, 0, 0, 0);
            z = __builtin_amdgcn_mfma_f32_16x16x32_bf16(Al[0], BW1[nt][0], z, 0, 0, 0);
            z = __builtin_amdgcn_mfma_f32_16x16x32_bf16(Ah[1], BW1[nt][1], z, 0, 0, 0);
            z = __builtin_amdgcn_mfma_f32_16x16x32_bf16(Al[1], BW1[nt][1], z, 0, 0, 0);
            acc[nt] = z;
        }

        // issue GEMM2 B-fragment loads; latency hides under epilogue 1
        bf16x8 B2[4][2];
        #pragma unroll
        for (int nt = 0; nt < 4; ++nt) {
            B2[nt][0] = __builtin_bit_cast(bf16x8, wb2[(nt*2 + 0)*64]);
            B2[nt][1] = __builtin_bit_cast(bf16x8, wb2[(nt*2 + 1)*64]);
        }

        // epilogue 1: silu+bias, bf16 store to wave tile (A2 layout), agg -> LDS
        int abn[4], emask[4];
        #pragma unroll
        for (int r2 = 0; r2 < 4; ++r2) {
            int e2 = kg*4 + r2;
            int eg2 = e0 + e2; if (eg2 >= NEDGE) eg2 = NEDGE - 1;
            abn[r2] = eg2 / NDEG;
            emask[r2] = (e2 < ecnt);
        }
        unsigned short* mw = mwall[w];
        #pragma unroll
        for (int nt = 0; nt < 4; ++nt) {
            int j = nt*16 + j0;
            float bv = vecs[2][j];
            #pragma unroll
            for (int r2 = 0; r2 < 4; ++r2) {
                float mv = silu_f(acc[nt][r2] + bv);
                mw[(kg*4 + r2)*MW2S + j] = bfu(mv);
                if (emask[r2]) atomicAdd(&aggL[abn[r2]][j], mv);
            }
        }

        // GEMM2 A-fragments: direct b128 reads from bf16 tile (no unpack)
        bf16x8 A2h[2];
        {
            const unsigned short* arp = mw + j0*MW2S;
            A2h[0] = *(const bf16x8*)(arp + kg*8);
            A2h[1] = *(const bf16x8*)(arp + 32 + kg*8);
        }

        // GEMM2: c1 = m @ Wc1 (hi-only; scal is 1e-3-scale via coord_w2 gain)
        f32x4 acc2[4];
        #pragma unroll
        for (int nt = 0; nt < 4; ++nt) {
            f32x4 z = {0.f, 0.f, 0.f, 0.f};
            z = __builtin_amdgcn_mfma_f32_16x16x32_bf16(A2h[0], B2[nt][0], z, 0, 0, 0);
            z = __builtin_amdgcn_mfma_f32_16x16x32_bf16(A2h[1], B2[nt][1], z, 0, 0, 0);
            acc2[nt] = z;
        }

        // epilogue 2: scal via 16-lane shuffle reduce, then dx -> LDS atomics
        float pr[4] = {0.f, 0.f, 0.f, 0.f};
        #pragma unroll
        for (int nt = 0; nt < 4; ++nt) {
            int j = nt*16 + j0;
            float cb = vecs[3][j], cw = vecs[4][j];
            #pragma unroll
            for (int r2 = 0; r2 < 4; ++r2)
                pr[r2] += silu_f(acc2[nt][r2] + cb) * cw;
        }
        #pragma unroll
        for (int off = 8; off > 0; off >>= 1) {
            #pragma unroll
            for (int r2 = 0; r2 < 4; ++r2)
                pr[r2] += __shfl_xor(pr[r2], off, 16);
        }
        if (j0 == 0) {
            #pragma unroll
            for (int r2 = 0; r2 < 4; ++r2)
                scal_sw[w][kg*4 + r2] = pr[r2];
        }
        if (l < ecnt) {
            float sc = scal_sw[w][l];
            atomicAdd(&dxL[a*3 + 0], f0*sc);
            atomicAdd(&dxL[a*3 + 1], f1*sc);
            atomicAdd(&dxL[a*3 + 2], f2*sc);
        }
    }
    __syncthreads();

    // stream results out: plain coalesced stores, no global atomics
    for (int i = tid; i < NPART*HID; i += 256) {
        int p = i >> 6, j = i & 63;
        aggw[(size_t)(batch*NPART + p)*HID + j] = aggL[p][j];
    }
    if (tid < 66) dxw[batch*66 + tid] = dxL[tid];
}

// ---- node kernel: node MLP + x update + next layer's Hr/Hc ----
__global__ __launch_bounds__(256, 4)
void k_node(const float* __restrict__ node_w1L, const float* __restrict__ node_b1L,
            const float* __restrict__ node_w2L, const float* __restrict__ node_b2L,
            const float* __restrict__ edge_w1n, const float* __restrict__ edge_b1n,
            float* __restrict__ xw, float* __restrict__ hw,
            float* __restrict__ Hrw, float* __restrict__ Hcw,
            const float* __restrict__ aggw, const float* __restrict__ dxw, int NT)
{
    __shared__ __align__(16) float hbuf[4][68], abuf[4][68];
    const int w = threadIdx.x >> 6, l = threadIdx.x & 63;
    const int n = blockIdx.x*4 + w;
    if (n >= NT) return;                      // no barriers in this kernel
    const int j = l;
    float hj = hw[n*HID + j];
    hbuf[w][j] = hj;
    abuf[w][j] = aggw[n*HID + j];
    float acc = node_b1L[j];
    #pragma unroll 4
    for (int k = 0; k < HID; ++k)
        acc += hbuf[w][k]*node_w1L[k*HID + j] + abuf[w][k]*node_w1L[(HID + k)*HID + j];
    float hn = silu_f(acc);
    abuf[w][j] = hn;
    float acc2 = node_b2L[j];
    #pragma unroll 4
    for (int k = 0; k < HID; ++k) acc2 += abuf[w][k]*node_w2L[k*HID + j];
    float hnew = hj + acc2;
    hw[n*HID + j] = hnew;
    hbuf[w][j] = hnew;
    float accr = edge_b1n[j], accc = 0.f;
    #pragma unroll 4
    for (int k = 0; k < HID; ++k) {
        float hk = hbuf[w][k];
        accr += hk*edge_w1n[k*HID + j];
        accc += hk*edge_w1n[(HID + k)*HID + j];
    }
    Hrw[n*HID + j] = accr;
    Hcw[n*HID + j] = accc;
    if (l < 3) xw[n*3 + l] += dxw[n*3 + l];
}

// ---- final: vel = (x + dx - x0) - mean ----
__global__ void k_final(const float* __restrict__ xw, const float* __restrict__ dxw,
                        const float* __restrict__ xs, float* __restrict__ out)
{
    __shared__ float vbuf[66];
    __shared__ float mv[3];
    const int b = blockIdx.x, t = threadIdx.x;
    if (t < 66) vbuf[t] = xw[b*66 + t] + dxw[b*66 + t] - xs[b*66 + t];
    __syncthreads();
    if (t < 3) {
        float s = 0.f;
        #pragma unroll
        for (int p = 0; p < NPART; ++p) s += vbuf[p*3 + t];
        mv[t] = s / (float)NPART;
    }
    __syncthreads();
    if (t < 66) out[b*66 + t] = vbuf[t] - mv[t % 3];
}

extern "C" void kernel_launch(void* const* d_in, const int* in_sizes, int n_in,
                              void* d_out, int out_size, void* d_ws, size_t ws_size,
                              hipStream_t stream) {
    const float* t_in     = (const float*)d_in[0];
    const float* xs       = (const float*)d_in[1];
    const float* h_init   = (const float*)d_in[2];
    const float* emb_w    = (const float*)d_in[3];
    const float* emb_b    = (const float*)d_in[4];
    const float* edge_w1  = (const float*)d_in[7];
    const float* edge_b1  = (const float*)d_in[8];
    const float* edge_w2  = (const float*)d_in[9];
    const float* edge_b2  = (const float*)d_in[10];
    const float* node_w1  = (const float*)d_in[11];
    const float* node_b1  = (const float*)d_in[12];
    const float* node_w2  = (const float*)d_in[13];
    const float* node_b2  = (const float*)d_in[14];
    const float* coord_w1 = (const float*)d_in[15];
    const float* coord_b1 = (const float*)d_in[16];
    const float* coord_w2 = (const float*)d_in[17];
    float* outp = (float*)d_out;

    const int NB = in_sizes[0];
    const int NT = NB * NPART;
    float* xw   = (float*)d_ws;           // NT*3
    float* hw   = xw   + (size_t)NT*3;    // NT*64
    float* Hrw  = hw   + (size_t)NT*HID;
    float* Hcw  = Hrw  + (size_t)NT*HID;
    float* aggw = Hcw  + (size_t)NT*HID;
    float* dxw  = aggw + (size_t)NT*HID;  // NT*3
    unsigned* wfrag = (unsigned*)(dxw + (size_t)NT*3);

    const int gNode = (NT + 3) / 4;

    prep_wfrag<<<8, 64, 0, stream>>>(edge_w2, coord_w1, wfrag);
    k_init<<<gNode, 256, 0, stream>>>(t_in, xs, h_init, emb_w, emb_b,
                                      edge_w1, edge_b1,
                                      xw, hw, Hrw, Hcw, dxw, NT);
    for (int L = 0; L < NLAYERS; ++L) {
        k_edge<<<NB, 256, 0, stream>>>(
            edge_w1 + L*130*HID + 128*HID,
            edge_b2 + L*HID, coord_b1 + L*HID, coord_w2 + L*HID,
            wfrag, xs, xw, Hrw, Hcw, aggw, dxw, L);
        if (L < NLAYERS - 1) {
            k_node<<<gNode, 256, 0, stream>>>(
                node_w1 + L*2*HID*HID, node_b1 + L*HID,
                node_w2 + L*HID*HID,   node_b2 + L*HID,
                edge_w1 + (L+1)*130*HID, edge_b1 + (L+1)*HID,
                xw, hw, Hrw, Hcw, aggw, dxw, NT);
        }
    }
    k_final<<<NB, 128, 0, stream>>>(xw, dxw, xs, outp);
}